// Round 7
// baseline (323.075 us; speedup 1.0000x reference)
//
#include <hip/hip_runtime.h>
#include <hip/hip_bf16.h>

typedef unsigned short u16t;

namespace {

constexpr int kB = 16, kD = 64, kN = 200, kT = 48, kH = 8;
constexpr float kEps = 1e-5f;

typedef __attribute__((ext_vector_type(8))) __bf16 bf16x8;
typedef __attribute__((ext_vector_type(4))) float f32x4;
union B8 { int4 i; bf16x8 v; u16t u[8]; };

__device__ __forceinline__ u16t f2bfu(float f) {
  union { __hip_bfloat16 h; u16t u; } c; c.h = __float2bfloat16(f); return c.u;
}
__device__ __forceinline__ float bfu2f(u16t u) {
  union { unsigned i; float f; } c; c.i = ((unsigned)u) << 16; return c.f;
}
__device__ __forceinline__ unsigned pk2(float a, float b) {
  return (unsigned)f2bfu(a) | ((unsigned)f2bfu(b) << 16);
}

// ---- workspace layout (u16 units) ----
constexpr int kWqOff = 0;
constexpr int kWkOff = 12288;
constexpr int kW1Off = 24576;
constexpr int kW2Off = 28672;
constexpr int kThOff = 32768;
constexpr int kAdjOff = 36864;                 // adj bf16 [200][200] = 40000 u16
// total (36864+40000)*2 = 153,728 bytes of d_ws

// ---------------- Kernel 0: one-time weight + adj bf16 pre-conversion ----------------
__global__ void k0_prep(const float* __restrict__ Wq, const float* __restrict__ Wk,
                        const float* __restrict__ W1, const float* __restrict__ W2,
                        const float* __restrict__ Theta, const float* __restrict__ adj,
                        u16t* __restrict__ ws) {
  const int tid = blockIdx.x * 256 + threadIdx.x;
  const int stride = gridDim.x * 256;
  for (int idx = tid; idx < 64 * 192; idx += stride) {
    const int row = idx / 192, rem = idx % 192;
    const int tap = rem >> 6, c = rem & 63;
    const int src = row * 192 + c * 3 + tap;   // Wq layout (D_out, D_in, 1, 3)
    ws[kWqOff + idx] = f2bfu(Wq[src]);
    ws[kWkOff + idx] = f2bfu(Wk[src]);
  }
  for (int idx = tid; idx < 4096; idx += stride) {
    ws[kW1Off + idx] = f2bfu(W1[idx]);
    ws[kW2Off + idx] = f2bfu(W2[idx]);
    ws[kThOff + idx] = f2bfu(Theta[idx]);
  }
  for (int idx = tid; idx < kN * kN; idx += stride)
    ws[kAdjOff + idx] = f2bfu(adj[idx]);
}

// ---------------- Kernel 1: temporal attention, fully MFMA (unchanged from R5) ----------------
__global__ __launch_bounds__(256, 4) void k1_temporal(
    const float* __restrict__ x, const u16t* __restrict__ ws,
    const float* __restrict__ bq, const float* __restrict__ bk,
    const float* __restrict__ b1, const float* __restrict__ b2,
    const float* __restrict__ g0, const float* __restrict__ beta0,
    float* __restrict__ hout)
{
  __shared__ __align__(16) float qs[3072];       // W2 out (LN input) [64][48]
  __shared__ __align__(16) u16t lds_h[13440];
  u16t* XT  = lds_h;            // [50][64]: elem(r,d) at r*64 + ((d/8 + r)&7)*8 + d%8 (rows 0,49 zero)
  u16t* osT = lds_h;            // overlay XT (dead after QKV): [48][64] same swizzle
  u16t* QT  = lds_h + 3200;     // [48][64]: elem(t,d) at t*64 + ((d/8 + t)&7)*8 + d%8
  u16t* KT  = lds_h + 6272;     // same layout
  u16t* VTT = lds_h + 9344;     // [64][64]: elem(d,s) at d*64 + ((s/8 + d)&7)*8 + s%8 (cols 48..63 zero)

  const int tid = threadIdx.x;
  const int b = blockIdx.x / kN, n = blockIdx.x % kN;
  const int wv = tid >> 6, lane = tid & 63;
  const int c15 = lane & 15, quad = lane >> 4;

  // ---- stage x[b,:,n,:] -> XT; zero-pad VTT cols 48..63 ----
  if (tid < 192) {
    const int dp = tid & 31, j = tid >> 5;
    const int d0 = dp * 2;
    const size_t xi = (size_t)b * (kD*kN*kT) + (size_t)d0 * (kN*kT) + (size_t)n * kT + j * 8;
    const float4 a0 = *(const float4*)(x + xi);
    const float4 a1 = *(const float4*)(x + xi + 4);
    const float4 c0 = *(const float4*)(x + xi + kN*kT);
    const float4 c1 = *(const float4*)(x + xi + kN*kT + 4);
    float f0[8] = {a0.x,a0.y,a0.z,a0.w,a1.x,a1.y,a1.z,a1.w};
    float f1[8] = {c0.x,c0.y,c0.z,c0.w,c1.x,c1.y,c1.z,c1.w};
    u16t* bb = XT + (d0 & 7);
    const int blk = d0 >> 3;
    #pragma unroll
    for (int e = 0; e < 8; ++e) {
      const int r = j*8 + e + 1;                 // row = t+1
      const unsigned pkd = (unsigned)f2bfu(f0[e]) | ((unsigned)f2bfu(f1[e]) << 16);
      *(unsigned*)(bb + r*64 + ((blk + r) & 7) * 8) = pkd;
    }
  } else if (tid < 208) {                        // XT rows 0 and 49 := 0
    const int g = tid - 192;
    const int rr = (g >> 3) ? 49 : 0, gg = g & 7;
    *(int4*)(XT + rr*64 + gg*8) = make_int4(0,0,0,0);
  }
  if (tid < 128) {                               // VTT cols 48..63 := 0
    const int d = tid >> 1, g = tid & 1;
    *(int4*)(VTT + d*64 + (((6 + g + d) & 7) << 3)) = make_int4(0,0,0,0);
  }
  __syncthreads();

  // ---- QKV via MFMA -> bf16 LDS (QT/KT/VTT) ----
  {
    const int dqr = wv*16 + c15;
    B8 aq[6], ak[6], av2[2];
    #pragma unroll
    for (int tap = 0; tap < 3; ++tap)
      #pragma unroll
      for (int ksp = 0; ksp < 2; ++ksp) {
        const int off = dqr*192 + tap*64 + ksp*32 + quad*8;
        aq[tap*2+ksp].i = *(const int4*)(ws + kWqOff + off);
        ak[tap*2+ksp].i = *(const int4*)(ws + kWkOff + off);
      }
    #pragma unroll
    for (int ksp = 0; ksp < 2; ++ksp)
      av2[ksp].i = *(const int4*)(ws + kW1Off + dqr*64 + ksp*32 + quad*8);
    float bqv[4], bkv[4], b1v[4];
    #pragma unroll
    for (int r = 0; r < 4; ++r) {
      const int row = wv*16 + quad*4 + r;
      bqv[r] = bq[row]; bkv[r] = bk[row]; b1v[r] = b1[row];
    }
    const int dbase = wv*16 + quad*4;
    const int dblk = dbase >> 3;
    constexpr float kScale = 0.35355339059327373f;  // 1/sqrt(DK), folded into Q

    for (int i = 0; i < 3; ++i) {
      const int t0 = i * 16;
      B8 bf[3][2];
      #pragma unroll
      for (int tap = 0; tap < 3; ++tap)
        #pragma unroll
        for (int ksp = 0; ksp < 2; ++ksp) {
          const int r = t0 + c15 + tap;
          bf[tap][ksp].i = *(const int4*)(XT + r*64 + (((ksp*4 + quad) + r) & 7)*8);
        }
      f32x4 accq = {0.f,0.f,0.f,0.f}, acck = {0.f,0.f,0.f,0.f}, accv = {0.f,0.f,0.f,0.f};
      #pragma unroll
      for (int tap = 0; tap < 3; ++tap)
        #pragma unroll
        for (int ksp = 0; ksp < 2; ++ksp) {
          accq = __builtin_amdgcn_mfma_f32_16x16x32_bf16(aq[tap*2+ksp].v, bf[tap][ksp].v, accq, 0, 0, 0);
          acck = __builtin_amdgcn_mfma_f32_16x16x32_bf16(ak[tap*2+ksp].v, bf[tap][ksp].v, acck, 0, 0, 0);
        }
      #pragma unroll
      for (int ksp = 0; ksp < 2; ++ksp)
        accv = __builtin_amdgcn_mfma_f32_16x16x32_bf16(av2[ksp].v, bf[1][ksp].v, accv, 0, 0, 0);

      const int t = t0 + c15;
      const int rotq = (dblk + t) & 7;
      const unsigned q01 = pk2((accq[0]+bqv[0])*kScale, (accq[1]+bqv[1])*kScale);
      const unsigned q23 = pk2((accq[2]+bqv[2])*kScale, (accq[3]+bqv[3])*kScale);
      *(int2*)(QT + t*64 + rotq*8 + (quad&1)*4) = make_int2((int)q01, (int)q23);
      const unsigned k01 = pk2(acck[0]+bkv[0], acck[1]+bkv[1]);
      const unsigned k23 = pk2(acck[2]+bkv[2], acck[3]+bkv[3]);
      *(int2*)(KT + t*64 + rotq*8 + (quad&1)*4) = make_int2((int)k01, (int)k23);
      #pragma unroll
      for (int r = 0; r < 4; ++r) {
        const int d = dbase + r;
        VTT[d*64 + ((((t>>3) + d) & 7) << 3) + (t & 7)] = f2bfu(accv[r] + b1v[r]);
      }
    }
  }
  __syncthreads();   // also protects XT reads before osT overlay writes

  // ---- attention via MFMA: wave wv handles heads 2wv, 2wv+1 (no-max softmax) ----
  #pragma unroll
  for (int hh = 0; hh < 2; ++hh) {
    const int h = wv*2 + hh;
    B8 vb[2];
    #pragma unroll
    for (int ksp = 0; ksp < 2; ++ksp) {
      if (c15 < 8) {
        const int dr = h*8 + c15;
        vb[ksp].i = *(const int4*)(VTT + dr*64 + (((ksp*4 + quad + dr) & 7) << 3));
      } else vb[ksp].i = make_int4(0,0,0,0);
    }
    #pragma unroll
    for (int nt = 0; nt < 3; ++nt) {
      B8 qb;
      if (quad == 0) {
        const int t = nt*16 + c15;
        qb.i = *(const int4*)(QT + t*64 + (((h + t) & 7) << 3));
      } else qb.i = make_int4(0,0,0,0);
      f32x4 sa[3];
      #pragma unroll
      for (int ms = 0; ms < 3; ++ms) {
        B8 ka;
        if (quad == 0) {
          const int s = ms*16 + c15;
          ka.i = *(const int4*)(KT + s*64 + (((h + s) & 7) << 3));
        } else ka.i = make_int4(0,0,0,0);
        f32x4 z = {0.f,0.f,0.f,0.f};
        sa[ms] = __builtin_amdgcn_mfma_f32_16x16x32_bf16(ka.v, qb.v, z, 0, 0, 0);
      }
      // no-max softmax: scores bounded, exp(s) safe in fp32
      float p[3][4]; float es = 0.f;
      #pragma unroll
      for (int ms = 0; ms < 3; ++ms)
        #pragma unroll
        for (int r = 0; r < 4; ++r) { p[ms][r] = __expf(sa[ms][r]); es += p[ms][r]; }
      es += __shfl_xor(es, 16, 64);
      es += __shfl_xor(es, 32, 64);
      const float inv = __fdividef(1.f, es);
      unsigned pkk[3][2];
      #pragma unroll
      for (int ms = 0; ms < 3; ++ms) {
        pkk[ms][0] = pk2(p[ms][0]*inv, p[ms][1]*inv);
        pkk[ms][1] = pk2(p[ms][2]*inv, p[ms][3]*inv);
      }
      // redistribute P -> PV A-frags (in-register, same-wave shfl)
      const int srcA = c15 + ((2*(quad & 1)) << 4);
      const int srcB = srcA + 16;
      const unsigned w0A = __shfl((int)pkk[0][0], srcA, 64), w0B = __shfl((int)pkk[1][0], srcA, 64);
      const unsigned w1A = __shfl((int)pkk[0][1], srcA, 64), w1B = __shfl((int)pkk[1][1], srcA, 64);
      const unsigned w2A = __shfl((int)pkk[0][0], srcB, 64), w2B = __shfl((int)pkk[1][0], srcB, 64);
      const unsigned w3A = __shfl((int)pkk[0][1], srcB, 64), w3B = __shfl((int)pkk[1][1], srcB, 64);
      const bool hi = quad >= 2;
      B8 a0;
      a0.i = make_int4((int)(hi ? w0B : w0A), (int)(hi ? w1B : w1A),
                       (int)(hi ? w2B : w2A), (int)(hi ? w3B : w3A));
      const int srcC = (c15 + ((2*quad) << 4)) & 63;
      const int srcD = (srcC + 16) & 63;
      const unsigned y0 = __shfl((int)pkk[2][0], srcC, 64), y1 = __shfl((int)pkk[2][1], srcC, 64);
      const unsigned y2 = __shfl((int)pkk[2][0], srcD, 64), y3 = __shfl((int)pkk[2][1], srcD, 64);
      B8 a1;
      if (quad < 2) a1.i = make_int4((int)y0, (int)y1, (int)y2, (int)y3);
      else          a1.i = make_int4(0,0,0,0);
      // PV
      f32x4 ov = {0.f,0.f,0.f,0.f};
      ov = __builtin_amdgcn_mfma_f32_16x16x32_bf16(a0.v, vb[0].v, ov, 0, 0, 0);
      ov = __builtin_amdgcn_mfma_f32_16x16x32_bf16(a1.v, vb[1].v, ov, 0, 0, 0);
      if (c15 < 8) {
        #pragma unroll
        for (int r = 0; r < 4; ++r) {
          const int t = nt*16 + quad*4 + r;
          osT[t*64 + (((h + t) & 7) << 3) + c15] = f2bfu(ov[r]);
        }
      }
    }
  }
  __syncthreads();

  // ---- W2 projection via MFMA -> qs ----
  {
    const int dqr = wv*16 + c15;
    B8 a2[2];
    #pragma unroll
    for (int ksp = 0; ksp < 2; ++ksp)
      a2[ksp].i = *(const int4*)(ws + kW2Off + dqr*64 + ksp*32 + quad*8);
    float b2v[4];
    #pragma unroll
    for (int r = 0; r < 4; ++r) b2v[r] = b2[wv*16 + quad*4 + r];
    for (int i = 0; i < 3; ++i) {
      const int t0 = i * 16;
      f32x4 acc = {0.f,0.f,0.f,0.f};
      #pragma unroll
      for (int ksp = 0; ksp < 2; ++ksp) {
        const int r = t0 + c15;
        B8 bo; bo.i = *(const int4*)(osT + r*64 + (((ksp*4 + quad) + r) & 7)*8);
        acc = __builtin_amdgcn_mfma_f32_16x16x32_bf16(a2[ksp].v, bo.v, acc, 0, 0, 0);
      }
      #pragma unroll
      for (int r = 0; r < 4; ++r)
        qs[(wv*16 + quad*4 + r)*48 + t0 + c15] = acc[r] + b2v[r];
    }
  }
  __syncthreads();

  // ---- LayerNorm + residual (scratch overlays dead XT/osT region) ----
  float* redm = reinterpret_cast<float*>(lds_h);      // [48][4]
  float* redv = redm + 192;                           // [48][4]
  float* mrs  = redm + 384;                           // [48]
  float* rrs  = redm + 432;                           // [48]
  if (tid < 192) {
    const int t = tid >> 2, grp = tid & 3;
    float sm = 0.f, sq = 0.f;
    #pragma unroll
    for (int i = 0; i < 16; ++i) {
      const float v = qs[(grp*16+i)*48 + t];
      sm += v; sq += v*v;
    }
    redm[t*4+grp] = sm; redv[t*4+grp] = sq;
  }
  __syncthreads();
  if (tid < 48) {
    const int t = tid;
    const float sm = redm[t*4] + redm[t*4+1] + redm[t*4+2] + redm[t*4+3];
    const float sq = redv[t*4] + redv[t*4+1] + redv[t*4+2] + redv[t*4+3];
    const float mean = sm * (1.f/64.f);
    const float var = sq * (1.f/64.f) - mean*mean;
    mrs[t] = mean; rrs[t] = rsqrtf(fmaxf(var, 0.f) + kEps);
  }
  __syncthreads();
  if (tid < 192) {
    const int t = tid >> 2, grp = tid & 3;
    const float mean = mrs[t], rs = rrs[t];
    const size_t base = (((size_t)b*kN + n)*kT + t)*kD + grp*16;
    const float* xp = x + (size_t)b*(kD*kN*kT) + (size_t)n*kT + t;
    #pragma unroll
    for (int i4 = 0; i4 < 4; ++i4) {
      float4 o;
      float* op = (float*)&o;
      #pragma unroll
      for (int e = 0; e < 4; ++e) {
        const int d = grp*16 + i4*4 + e;
        const float tout = qs[d*48 + t];
        const float xv = xp[(size_t)d * (kN*kT)];
        op[e] = xv + (tout - mean)*rs*g0[d] + beta0[d];
      }
      *(float4*)(hout + base + i4*4) = o;
    }
  }
}

// ---------------- Kernel 2: spatial GCN, 8 waves, bf16 adj, coalesced epilogue ----------------
// 768 blocks x 512 thr; LDS 47.1 KB -> 3 blocks/CU = 24 waves/CU (6/SIMD).
// sout epilogue overlays Wb -> the 2 unused padding groups per row are re-zeroed
// every chunk (they feed MFMA B with a zero A-frag: must not be NaN/Inf).
// adj padding columns (m >= kN) forced to 0 (no OOB read of bf16 adj cache).
__global__ __launch_bounds__(512, 6) void k2_spatial_mfma(
    float* __restrict__ hio, const u16t* __restrict__ adjb,
    const u16t* __restrict__ ws, const float* __restrict__ g1,
    const float* __restrict__ beta1)
{
  __shared__ __align__(16) u16t Hs[208*64];
  __shared__ __align__(16) u16t Wb[32*224];          // overlaid by sout[32][68] fp32 in epilogue
  __shared__ __align__(16) u16t A2[32*64];
  __shared__ __align__(16) float rsumT[32][8];
  __shared__ float lnS[4][32], lnQ[4][32];

  const int tid = threadIdx.x;
  const int b = blockIdx.x / kT, t = blockIdx.x % kT;
  const int wv = tid >> 6, lane = tid & 63;
  const int c15 = lane & 15, quad = lane >> 4;
  const int dt = wv & 3, so = wv >> 2;          // owner d-tile / sub for agg,theta,LN
  const int nti = (wv < 5) ? 2 : 1;             // m-tiles: {wv} + {wv+8 if wv<5}
  const int dq = dt*16 + c15;

  const float g1f = g1[dq], be1f = beta1[dq];
  B8 bth[2];
  #pragma unroll
  for (int ksp = 0; ksp < 2; ++ksp)
    bth[ksp].i = *(const int4*)(ws + kThOff + dq*64 + ksp*32 + quad*8);

  // ---- stage H -> Hs (bf16, rot-swizzled); zero rows 200..207 ----
  for (int idx = tid; idx < kN*8; idx += 512) {
    const int n = idx >> 3, j = idx & 7;
    const float* src = hio + (((size_t)b*kN + n)*kT + t)*kD + j*8;
    const float4 p0 = *(const float4*)src, p1 = *(const float4*)(src + 4);
    B8 p;
    p.u[0]=f2bfu(p0.x); p.u[1]=f2bfu(p0.y); p.u[2]=f2bfu(p0.z); p.u[3]=f2bfu(p0.w);
    p.u[4]=f2bfu(p1.x); p.u[5]=f2bfu(p1.y); p.u[6]=f2bfu(p1.z); p.u[7]=f2bfu(p1.w);
    *(int4*)(Hs + n*64 + (((j + n) & 7) << 3)) = p.i;
  }
  if (tid < 64)
    *(int4*)(Hs + (200 + (tid >> 3))*64 + ((tid & 7) << 3)) = make_int4(0,0,0,0);
  for (int idx = tid; idx < (32*224)/8; idx += 512)
    *(int4*)(Wb + idx*8) = make_int4(0,0,0,0);
  __syncthreads();

  // ---- hoisted agg A-fragments: A[row=dq][k=m] = H[m][dq] ----
  B8 ahi[7];
  #pragma unroll
  for (int ksp = 0; ksp < 6; ++ksp) {
    #pragma unroll
    for (int j = 0; j < 8; ++j) {
      const int m = ksp*32 + quad*8 + j;
      ahi[ksp].u[j] = Hs[m*64 + ((((dq>>3) + m) & 7) << 3) + (dq & 7)];
    }
  }
  if (quad == 0) {
    #pragma unroll
    for (int j = 0; j < 8; ++j) {
      const int m = 192 + j;
      ahi[6].u[j] = Hs[m*64 + ((((dq>>3) + m) & 7) << 3) + (dq & 7)];
    }
  } else {
    ahi[6].i = make_int4(0, 0, 0, 0);
  }

  for (int cc = 0; cc < 7; ++cc) {
    const int n0 = cc * 32;
    const bool hasB = (cc < 6);
    const bool act = (so == 0) || hasB;

    // ---- scores: this wave's m-tiles vs both row sub-blocks ----
    B8 afr0[2], afr1[2];
    #pragma unroll
    for (int ksp = 0; ksp < 2; ++ksp) {
      const int rowA = n0 + c15;
      afr0[ksp].i = *(const int4*)(Hs + rowA*64 + (((ksp*4 + quad + rowA) & 7) << 3));
      if (hasB) {
        const int rowB = rowA + 16;
        afr1[ksp].i = *(const int4*)(Hs + rowB*64 + (((ksp*4 + quad + rowB) & 7) << 3));
      } else afr1[ksp].i = make_int4(0,0,0,0);
    }
    f32x4 a00 = {0.f,0.f,0.f,0.f}, a01 = {0.f,0.f,0.f,0.f};
    f32x4 a10 = {0.f,0.f,0.f,0.f}, a11 = {0.f,0.f,0.f,0.f};
    #pragma unroll
    for (int ksp = 0; ksp < 2; ++ksp) {
      {
        const int row = wv*16 + c15;
        B8 bfr; bfr.i = *(const int4*)(Hs + row*64 + (((ksp*4 + quad + row) & 7) << 3));
        a00 = __builtin_amdgcn_mfma_f32_16x16x32_bf16(afr0[ksp].v, bfr.v, a00, 0, 0, 0);
        if (hasB) a10 = __builtin_amdgcn_mfma_f32_16x16x32_bf16(afr1[ksp].v, bfr.v, a10, 0, 0, 0);
      }
      if (nti == 2) {
        const int row = (wv + 8)*16 + c15;
        B8 bfr; bfr.i = *(const int4*)(Hs + row*64 + (((ksp*4 + quad + row) & 7) << 3));
        a01 = __builtin_amdgcn_mfma_f32_16x16x32_bf16(afr0[ksp].v, bfr.v, a01, 0, 0, 0);
        if (hasB) a11 = __builtin_amdgcn_mfma_f32_16x16x32_bf16(afr1[ksp].v, bfr.v, a11, 0, 0, 0);
      }
    }
    // no-max exp + per-wave row-sum partials
    float p00[4], p01[4], p10[4], p11[4], smr0[4], smr1[4];
    #pragma unroll
    for (int r = 0; r < 4; ++r) {
      p00[r] = __expf(fmaf(a00[r], 0.125f, -20.f));
      p01[r] = (nti == 2) ? __expf(fmaf(a01[r], 0.125f, -20.f)) : 0.f;
      smr0[r] = p00[r] + p01[r];
      p10[r] = hasB ? __expf(fmaf(a10[r], 0.125f, -20.f)) : 0.f;
      p11[r] = (hasB && nti == 2) ? __expf(fmaf(a11[r], 0.125f, -20.f)) : 0.f;
      smr1[r] = p10[r] + p11[r];
    }
    #pragma unroll
    for (int off = 1; off <= 8; off <<= 1)
      #pragma unroll
      for (int r = 0; r < 4; ++r) {
        smr0[r] += __shfl_xor(smr0[r], off, 64);
        smr1[r] += __shfl_xor(smr1[r], off, 64);
      }
    if (c15 == 0) {
      #pragma unroll
      for (int r = 0; r < 4; ++r) rsumT[quad*4 + r][wv] = smr0[r];
      if (hasB) {
        #pragma unroll
        for (int r = 0; r < 4; ++r) rsumT[16 + quad*4 + r][wv] = smr1[r];
      }
    }
    __syncthreads();

    // ---- Wb fill (this wave's m-tiles; adj from bf16 cache, padding cols -> 0) ----
    // Re-zero the 2 per-row padding groups that the sout overlay may have clobbered
    // (they're read by the agg MFMA against a zero A-frag; NaN/Inf would poison it).
    if (tid < 64) {
      const int row = tid >> 1;
      int g = row + 26 + (tid & 1);
      if (g >= 28) g -= 28;
      *(int4*)(Wb + row*224 + g*8) = make_int4(0,0,0,0);
    }
    #pragma unroll
    for (int sub = 0; sub < 2; ++sub) {
      if (sub == 1 && !hasB) break;
      #pragma unroll
      for (int r = 0; r < 4; ++r) {
        const int RR = sub*16 + quad*4 + r;
        const float4 s0 = *(const float4*)&rsumT[RR][0];
        const float4 s1 = *(const float4*)&rsumT[RR][4];
        const float tot = ((s0.x + s0.y) + (s0.z + s0.w)) + ((s1.x + s1.y) + (s1.z + s1.w));
        const float inv = __fdividef(0.125f, fmaxf(tot, 1e-30f));
        const int n = n0 + RR;
        const int na = (n < kN) ? n : (kN - 1);
        {
          const int m = wv*16 + c15;               // always < 128 < kN
          const float pv = sub ? p10[r] : p00[r];
          const float w = pv * inv * bfu2f(adjb[(size_t)na*kN + m]);
          int g = wv*2 + (c15 >> 3) + RR;
          if (g >= 28) g -= 28;
          Wb[RR*224 + g*8 + (c15 & 7)] = f2bfu(w);
        }
        if (nti == 2) {
          const int m = (wv + 8)*16 + c15;
          const float av = (m < kN) ? bfu2f(adjb[(size_t)na*kN + m]) : 0.f;
          const float pv = sub ? p11[r] : p01[r];
          const float w = pv * inv * av;
          int g = (wv + 8)*2 + (c15 >> 3) + RR;
          if (g >= 28) g -= 28;
          if (g >= 28) g -= 28;
          Wb[RR*224 + g*8 + (c15 & 7)] = f2bfu(w);
        }
      }
    }
    __syncthreads();

    // ---- agg: one (sub, d-tile) per wave; 4+3 split chains ----
    float vr[4];
    if (act) {
      const int RRr = so*16 + c15;
      f32x4 ag0 = {0.f,0.f,0.f,0.f}, ag1 = {0.f,0.f,0.f,0.f};
      #pragma unroll
      for (int ksp = 0; ksp < 7; ++ksp) {
        int g = ksp*4 + quad + RRr;
        if (g >= 28) g -= 28;
        if (g >= 28) g -= 28;
        B8 bw; bw.i = *(const int4*)(Wb + RRr*224 + g*8);
        if (ksp & 1) ag1 = __builtin_amdgcn_mfma_f32_16x16x32_bf16(ahi[ksp].v, bw.v, ag1, 0, 0, 0);
        else         ag0 = __builtin_amdgcn_mfma_f32_16x16x32_bf16(ahi[ksp].v, bw.v, ag0, 0, 0, 0);
      }
      #pragma unroll
      for (int r = 0; r < 4; ++r) {
        const int d = dt*16 + quad*4 + r;
        A2[RRr*64 + ((((d>>3) + RRr) & 7) << 3) + (d & 7)] = f2bfu(ag0[r] + ag1[r]);
      }
    }
    __syncthreads();

    // ---- theta + relu + LN partials ----
    if (act) {
      const int R = so*16 + c15;
      f32x4 o = {0.f,0.f,0.f,0.f};
      #pragma unroll
      for (int ksp = 0; ksp < 2; ++ksp) {
        B8 a; a.i = *(const int4*)(A2 + R*64 + (((ksp*4 + quad + R) & 7) << 3));
        o = __builtin_amdgcn_mfma_f32_16x16x32_bf16(a.v, bth[ksp].v, o, 0, 0, 0);
      }
      float ps[4], pq[4];
      #pragma unroll
      for (int r = 0; r < 4; ++r) {
        vr[r] = fmaxf(o[r], 0.f);
        ps[r] = vr[r]; pq[r] = vr[r]*vr[r];
      }
      #pragma unroll
      for (int off = 1; off <= 8; off <<= 1)
        #pragma unroll
        for (int r = 0; r < 4; ++r) {
          ps[r] += __shfl_xor(ps[r], off, 64);
          pq[r] += __shfl_xor(pq[r], off, 64);
        }
      if (c15 == 0) {
        #pragma unroll
        for (int r = 0; r < 4; ++r) {
          lnS[dt][so*16 + quad*4 + r] = ps[r];
          lnQ[dt][so*16 + quad*4 + r] = pq[r];
        }
      }
    }
    __syncthreads();

    // ---- finalize LN -> sout LDS tile (overlay on dead Wb), then coalesced RMW ----
    float* soutL = reinterpret_cast<float*>(Wb);    // [32][68] fp32 = 8704 B < 14336 B
    if (act) {
      #pragma unroll
      for (int r = 0; r < 4; ++r) {
        const int RR = so*16 + quad*4 + r;
        const float S = lnS[0][RR] + lnS[1][RR] + lnS[2][RR] + lnS[3][RR];
        const float Q = lnQ[0][RR] + lnQ[1][RR] + lnQ[2][RR] + lnQ[3][RR];
        const float mean = S * (1.f/64.f);
        const float var = Q * (1.f/64.f) - mean*mean;
        const float rs = rsqrtf(fmaxf(var, 0.f) + kEps);
        soutL[RR*68 + dq] = (vr[r] - mean)*rs*g1f + be1f;
      }
    }
    __syncthreads();
    {
      const int row = tid >> 4, c4v = tid & 15;     // 32 rows x 16 float4 = 512 threads
      const int n = n0 + row;
      if (n < kN) {
        const float4 sv = *(const float4*)&soutL[row*68 + c4v*4];
        float* hp = hio + (((size_t)b*kN + n)*kT + t)*kD + c4v*4;
        float4 hv = *(const float4*)hp;
        hv.x += sv.x; hv.y += sv.y; hv.z += sv.z; hv.w += sv.w;
        *(float4*)hp = hv;
      }
    }
    __syncthreads();   // protect soutL (=Wb) before next chunk's Wb fill
  }
}

} // namespace

extern "C" void kernel_launch(void* const* d_in, const int* in_sizes, int n_in,
                              void* d_out, int out_size, void* d_ws, size_t ws_size,
                              hipStream_t stream) {
  const float* x     = (const float*)d_in[0];
  const float* adj   = (const float*)d_in[1];
  const float* Wq    = (const float*)d_in[2];
  const float* bq    = (const float*)d_in[3];
  const float* Wk    = (const float*)d_in[4];
  const float* bk    = (const float*)d_in[5];
  const float* W1    = (const float*)d_in[6];
  const float* b1    = (const float*)d_in[7];
  const float* W2    = (const float*)d_in[8];
  const float* b2    = (const float*)d_in[9];
  const float* Theta = (const float*)d_in[10];
  const float* g0    = (const float*)d_in[11];
  const float* beta0 = (const float*)d_in[12];
  const float* g1    = (const float*)d_in[13];
  const float* beta1 = (const float*)d_in[14];

  float* hbuf = (float*)d_out;       // h staged in-place through d_out (fp32)
  u16t* wsb = (u16t*)d_ws;           // bf16 weight + adj cache (153,728 B)

  k0_prep<<<dim3(48), dim3(256), 0, stream>>>(Wq, Wk, W1, W2, Theta, adj, wsb);
  k1_temporal<<<dim3(kB*kN), dim3(256), 0, stream>>>(
      x, wsb, bq, bk, b1, b2, g0, beta0, hbuf);
  k2_spatial_mfma<<<dim3(kB*kT), dim3(512), 0, stream>>>(
      hbuf, wsb + kAdjOff, wsb, g1, beta1);
}

// Round 10
// 314.671 us; speedup vs baseline: 1.0267x; 1.0267x over previous
//
#include <hip/hip_runtime.h>
#include <hip/hip_bf16.h>

typedef unsigned short u16t;

namespace {

constexpr int kB = 16, kD = 64, kN = 200, kT = 48, kH = 8;
constexpr float kEps = 1e-5f;

typedef __attribute__((ext_vector_type(8))) __bf16 bf16x8;
typedef __attribute__((ext_vector_type(4))) float f32x4;
union B8 { int4 i; bf16x8 v; u16t u[8]; };

__device__ __forceinline__ u16t f2bfu(float f) {
  union { __hip_bfloat16 h; u16t u; } c; c.h = __float2bfloat16(f); return c.u;
}
__device__ __forceinline__ float bfu2f(u16t u) {
  union { unsigned i; float f; } c; c.i = ((unsigned)u) << 16; return c.f;
}
__device__ __forceinline__ unsigned pk2(float a, float b) {
  return (unsigned)f2bfu(a) | ((unsigned)f2bfu(b) << 16);
}

// ---- workspace layout ----
// u16 units:
constexpr int kWqOff = 0;
constexpr int kWkOff = 12288;
constexpr int kW1Off = 24576;
constexpr int kW2Off = 28672;
constexpr int kThOff = 32768;
constexpr int kAdjPOff = 36864;                // swizzled adj bf16: 7*13*2*4*64 = 46592 u16
constexpr int kAdjPPerChunk = 13*2*4*64;       // 6656
// bytes:
constexpr size_t kHOffBytes = 167936;          // (36864+46592)*2 = 166912, rounded up
constexpr size_t kHBytes = (size_t)kB * kN * kT * kD * 4;   // 39,321,600

// ---------------- Kernel 0: weight bf16 pre-conversion + adj pre-swizzle ----------------
__global__ void k0_prep(const float* __restrict__ Wq, const float* __restrict__ Wk,
                        const float* __restrict__ W1, const float* __restrict__ W2,
                        const float* __restrict__ Theta, const float* __restrict__ adj,
                        u16t* __restrict__ ws) {
  const int tid = blockIdx.x * 256 + threadIdx.x;
  const int stride = gridDim.x * 256;
  for (int idx = tid; idx < 64 * 192; idx += stride) {
    const int row = idx / 192, rem = idx % 192;
    const int tap = rem >> 6, c = rem & 63;
    const int src = row * 192 + c * 3 + tap;   // Wq layout (D_out, D_in, 1, 3)
    ws[kWqOff + idx] = f2bfu(Wq[src]);
    ws[kWkOff + idx] = f2bfu(Wk[src]);
  }
  for (int idx = tid; idx < 4096; idx += stride) {
    ws[kW1Off + idx] = f2bfu(W1[idx]);
    ws[kW2Off + idx] = f2bfu(W2[idx]);
    ws[kThOff + idx] = f2bfu(Theta[idx]);
  }
  // adjP[cc][pair=mt*2+sub][r][lane]: lane=(quad,c15); RR=sub*16+quad*4+r;
  // value = adj[min(cc*32+RR,199)][mt*16+c15], 0 for padding cols m>=200.
  for (int idx = tid; idx < 7 * kAdjPPerChunk; idx += stride) {
    const int cc = idx / kAdjPPerChunk, rem = idx % kAdjPPerChunk;
    const int pair = rem >> 8, rem2 = rem & 255;
    const int mt = pair >> 1, sub = pair & 1;
    const int r = rem2 >> 6, lane = rem2 & 63;
    const int quad = lane >> 4, c15 = lane & 15;
    const int RR = sub*16 + quad*4 + r;
    const int n = cc*32 + RR;
    const int na = (n < kN) ? n : (kN - 1);
    const int m = mt*16 + c15;
    ws[kAdjPOff + idx] = (m < kN) ? f2bfu(adj[(size_t)na*kN + m]) : (u16t)0;
  }
}

// ---------------- Kernel 1: temporal attention, fully MFMA (unchanged) ----------------
__global__ __launch_bounds__(256, 4) void k1_temporal(
    const float* __restrict__ x, const u16t* __restrict__ ws,
    const float* __restrict__ bq, const float* __restrict__ bk,
    const float* __restrict__ b1, const float* __restrict__ b2,
    const float* __restrict__ g0, const float* __restrict__ beta0,
    float* __restrict__ hout)
{
  __shared__ __align__(16) float qs[3072];       // W2 out (LN input) [64][48]
  __shared__ __align__(16) u16t lds_h[13440];
  u16t* XT  = lds_h;            // [50][64]: elem(r,d) at r*64 + ((d/8 + r)&7)*8 + d%8 (rows 0,49 zero)
  u16t* osT = lds_h;            // overlay XT (dead after QKV): [48][64] same swizzle
  u16t* QT  = lds_h + 3200;     // [48][64]: elem(t,d) at t*64 + ((d/8 + t)&7)*8 + d%8
  u16t* KT  = lds_h + 6272;     // same layout
  u16t* VTT = lds_h + 9344;     // [64][64]: elem(d,s) at d*64 + ((s/8 + d)&7)*8 + s%8 (cols 48..63 zero)

  const int tid = threadIdx.x;
  const int b = blockIdx.x / kN, n = blockIdx.x % kN;
  const int wv = tid >> 6, lane = tid & 63;
  const int c15 = lane & 15, quad = lane >> 4;

  // ---- stage x[b,:,n,:] -> XT; zero-pad VTT cols 48..63 ----
  if (tid < 192) {
    const int dp = tid & 31, j = tid >> 5;
    const int d0 = dp * 2;
    const size_t xi = (size_t)b * (kD*kN*kT) + (size_t)d0 * (kN*kT) + (size_t)n * kT + j * 8;
    const float4 a0 = *(const float4*)(x + xi);
    const float4 a1 = *(const float4*)(x + xi + 4);
    const float4 c0 = *(const float4*)(x + xi + kN*kT);
    const float4 c1 = *(const float4*)(x + xi + kN*kT + 4);
    float f0[8] = {a0.x,a0.y,a0.z,a0.w,a1.x,a1.y,a1.z,a1.w};
    float f1[8] = {c0.x,c0.y,c0.z,c0.w,c1.x,c1.y,c1.z,c1.w};
    u16t* bb = XT + (d0 & 7);
    const int blk = d0 >> 3;
    #pragma unroll
    for (int e = 0; e < 8; ++e) {
      const int r = j*8 + e + 1;                 // row = t+1
      const unsigned pkd = (unsigned)f2bfu(f0[e]) | ((unsigned)f2bfu(f1[e]) << 16);
      *(unsigned*)(bb + r*64 + ((blk + r) & 7) * 8) = pkd;
    }
  } else if (tid < 208) {                        // XT rows 0 and 49 := 0
    const int g = tid - 192;
    const int rr = (g >> 3) ? 49 : 0, gg = g & 7;
    *(int4*)(XT + rr*64 + gg*8) = make_int4(0,0,0,0);
  }
  if (tid < 128) {                               // VTT cols 48..63 := 0
    const int d = tid >> 1, g = tid & 1;
    *(int4*)(VTT + d*64 + (((6 + g + d) & 7) << 3)) = make_int4(0,0,0,0);
  }
  __syncthreads();

  // ---- QKV via MFMA -> bf16 LDS (QT/KT/VTT) ----
  {
    const int dqr = wv*16 + c15;
    B8 aq[6], ak[6], av2[2];
    #pragma unroll
    for (int tap = 0; tap < 3; ++tap)
      #pragma unroll
      for (int ksp = 0; ksp < 2; ++ksp) {
        const int off = dqr*192 + tap*64 + ksp*32 + quad*8;
        aq[tap*2+ksp].i = *(const int4*)(ws + kWqOff + off);
        ak[tap*2+ksp].i = *(const int4*)(ws + kWkOff + off);
      }
    #pragma unroll
    for (int ksp = 0; ksp < 2; ++ksp)
      av2[ksp].i = *(const int4*)(ws + kW1Off + dqr*64 + ksp*32 + quad*8);
    float bqv[4], bkv[4], b1v[4];
    #pragma unroll
    for (int r = 0; r < 4; ++r) {
      const int row = wv*16 + quad*4 + r;
      bqv[r] = bq[row]; bkv[r] = bk[row]; b1v[r] = b1[row];
    }
    const int dbase = wv*16 + quad*4;
    const int dblk = dbase >> 3;
    constexpr float kScale = 0.35355339059327373f;  // 1/sqrt(DK), folded into Q

    for (int i = 0; i < 3; ++i) {
      const int t0 = i * 16;
      B8 bf[3][2];
      #pragma unroll
      for (int tap = 0; tap < 3; ++tap)
        #pragma unroll
        for (int ksp = 0; ksp < 2; ++ksp) {
          const int r = t0 + c15 + tap;
          bf[tap][ksp].i = *(const int4*)(XT + r*64 + (((ksp*4 + quad) + r) & 7)*8);
        }
      f32x4 accq = {0.f,0.f,0.f,0.f}, acck = {0.f,0.f,0.f,0.f}, accv = {0.f,0.f,0.f,0.f};
      #pragma unroll
      for (int tap = 0; tap < 3; ++tap)
        #pragma unroll
        for (int ksp = 0; ksp < 2; ++ksp) {
          accq = __builtin_amdgcn_mfma_f32_16x16x32_bf16(aq[tap*2+ksp].v, bf[tap][ksp].v, accq, 0, 0, 0);
          acck = __builtin_amdgcn_mfma_f32_16x16x32_bf16(ak[tap*2+ksp].v, bf[tap][ksp].v, acck, 0, 0, 0);
        }
      #pragma unroll
      for (int ksp = 0; ksp < 2; ++ksp)
        accv = __builtin_amdgcn_mfma_f32_16x16x32_bf16(av2[ksp].v, bf[1][ksp].v, accv, 0, 0, 0);

      const int t = t0 + c15;
      const int rotq = (dblk + t) & 7;
      const unsigned q01 = pk2((accq[0]+bqv[0])*kScale, (accq[1]+bqv[1])*kScale);
      const unsigned q23 = pk2((accq[2]+bqv[2])*kScale, (accq[3]+bqv[3])*kScale);
      *(int2*)(QT + t*64 + rotq*8 + (quad&1)*4) = make_int2((int)q01, (int)q23);
      const unsigned k01 = pk2(acck[0]+bkv[0], acck[1]+bkv[1]);
      const unsigned k23 = pk2(acck[2]+bkv[2], acck[3]+bkv[3]);
      *(int2*)(KT + t*64 + rotq*8 + (quad&1)*4) = make_int2((int)k01, (int)k23);
      #pragma unroll
      for (int r = 0; r < 4; ++r) {
        const int d = dbase + r;
        VTT[d*64 + ((((t>>3) + d) & 7) << 3) + (t & 7)] = f2bfu(accv[r] + b1v[r]);
      }
    }
  }
  __syncthreads();   // also protects XT reads before osT overlay writes

  // ---- attention via MFMA: wave wv handles heads 2wv, 2wv+1 (no-max softmax) ----
  #pragma unroll
  for (int hh = 0; hh < 2; ++hh) {
    const int h = wv*2 + hh;
    B8 vb[2];
    #pragma unroll
    for (int ksp = 0; ksp < 2; ++ksp) {
      if (c15 < 8) {
        const int dr = h*8 + c15;
        vb[ksp].i = *(const int4*)(VTT + dr*64 + (((ksp*4 + quad + dr) & 7) << 3));
      } else vb[ksp].i = make_int4(0,0,0,0);
    }
    #pragma unroll
    for (int nt = 0; nt < 3; ++nt) {
      B8 qb;
      if (quad == 0) {
        const int t = nt*16 + c15;
        qb.i = *(const int4*)(QT + t*64 + (((h + t) & 7) << 3));
      } else qb.i = make_int4(0,0,0,0);
      f32x4 sa[3];
      #pragma unroll
      for (int ms = 0; ms < 3; ++ms) {
        B8 ka;
        if (quad == 0) {
          const int s = ms*16 + c15;
          ka.i = *(const int4*)(KT + s*64 + (((h + s) & 7) << 3));
        } else ka.i = make_int4(0,0,0,0);
        f32x4 z = {0.f,0.f,0.f,0.f};
        sa[ms] = __builtin_amdgcn_mfma_f32_16x16x32_bf16(ka.v, qb.v, z, 0, 0, 0);
      }
      // no-max softmax: scores bounded, exp(s) safe in fp32
      float p[3][4]; float es = 0.f;
      #pragma unroll
      for (int ms = 0; ms < 3; ++ms)
        #pragma unroll
        for (int r = 0; r < 4; ++r) { p[ms][r] = __expf(sa[ms][r]); es += p[ms][r]; }
      es += __shfl_xor(es, 16, 64);
      es += __shfl_xor(es, 32, 64);
      const float inv = __fdividef(1.f, es);
      unsigned pkk[3][2];
      #pragma unroll
      for (int ms = 0; ms < 3; ++ms) {
        pkk[ms][0] = pk2(p[ms][0]*inv, p[ms][1]*inv);
        pkk[ms][1] = pk2(p[ms][2]*inv, p[ms][3]*inv);
      }
      // redistribute P -> PV A-frags (in-register, same-wave shfl)
      const int srcA = c15 + ((2*(quad & 1)) << 4);
      const int srcB = srcA + 16;
      const unsigned w0A = __shfl((int)pkk[0][0], srcA, 64), w0B = __shfl((int)pkk[1][0], srcA, 64);
      const unsigned w1A = __shfl((int)pkk[0][1], srcA, 64), w1B = __shfl((int)pkk[1][1], srcA, 64);
      const unsigned w2A = __shfl((int)pkk[0][0], srcB, 64), w2B = __shfl((int)pkk[1][0], srcB, 64);
      const unsigned w3A = __shfl((int)pkk[0][1], srcB, 64), w3B = __shfl((int)pkk[1][1], srcB, 64);
      const bool hi = quad >= 2;
      B8 a0;
      a0.i = make_int4((int)(hi ? w0B : w0A), (int)(hi ? w1B : w1A),
                       (int)(hi ? w2B : w2A), (int)(hi ? w3B : w3A));
      const int srcC = (c15 + ((2*quad) << 4)) & 63;
      const int srcD = (srcC + 16) & 63;
      const unsigned y0 = __shfl((int)pkk[2][0], srcC, 64), y1 = __shfl((int)pkk[2][1], srcC, 64);
      const unsigned y2 = __shfl((int)pkk[2][0], srcD, 64), y3 = __shfl((int)pkk[2][1], srcD, 64);
      B8 a1;
      if (quad < 2) a1.i = make_int4((int)y0, (int)y1, (int)y2, (int)y3);
      else          a1.i = make_int4(0,0,0,0);
      // PV
      f32x4 ov = {0.f,0.f,0.f,0.f};
      ov = __builtin_amdgcn_mfma_f32_16x16x32_bf16(a0.v, vb[0].v, ov, 0, 0, 0);
      ov = __builtin_amdgcn_mfma_f32_16x16x32_bf16(a1.v, vb[1].v, ov, 0, 0, 0);
      if (c15 < 8) {
        #pragma unroll
        for (int r = 0; r < 4; ++r) {
          const int t = nt*16 + quad*4 + r;
          osT[t*64 + (((h + t) & 7) << 3) + c15] = f2bfu(ov[r]);
        }
      }
    }
  }
  __syncthreads();

  // ---- W2 projection via MFMA -> qs ----
  {
    const int dqr = wv*16 + c15;
    B8 a2[2];
    #pragma unroll
    for (int ksp = 0; ksp < 2; ++ksp)
      a2[ksp].i = *(const int4*)(ws + kW2Off + dqr*64 + ksp*32 + quad*8);
    float b2v[4];
    #pragma unroll
    for (int r = 0; r < 4; ++r) b2v[r] = b2[wv*16 + quad*4 + r];
    for (int i = 0; i < 3; ++i) {
      const int t0 = i * 16;
      f32x4 acc = {0.f,0.f,0.f,0.f};
      #pragma unroll
      for (int ksp = 0; ksp < 2; ++ksp) {
        const int r = t0 + c15;
        B8 bo; bo.i = *(const int4*)(osT + r*64 + (((ksp*4 + quad) + r) & 7)*8);
        acc = __builtin_amdgcn_mfma_f32_16x16x32_bf16(a2[ksp].v, bo.v, acc, 0, 0, 0);
      }
      #pragma unroll
      for (int r = 0; r < 4; ++r)
        qs[(wv*16 + quad*4 + r)*48 + t0 + c15] = acc[r] + b2v[r];
    }
  }
  __syncthreads();

  // ---- LayerNorm + residual (scratch overlays dead XT/osT region) ----
  float* redm = reinterpret_cast<float*>(lds_h);      // [48][4]
  float* redv = redm + 192;                           // [48][4]
  float* mrs  = redm + 384;                           // [48]
  float* rrs  = redm + 432;                           // [48]
  if (tid < 192) {
    const int t = tid >> 2, grp = tid & 3;
    float sm = 0.f, sq = 0.f;
    #pragma unroll
    for (int i = 0; i < 16; ++i) {
      const float v = qs[(grp*16+i)*48 + t];
      sm += v; sq += v*v;
    }
    redm[t*4+grp] = sm; redv[t*4+grp] = sq;
  }
  __syncthreads();
  if (tid < 48) {
    const int t = tid;
    const float sm = redm[t*4] + redm[t*4+1] + redm[t*4+2] + redm[t*4+3];
    const float sq = redv[t*4] + redv[t*4+1] + redv[t*4+2] + redv[t*4+3];
    const float mean = sm * (1.f/64.f);
    const float var = sq * (1.f/64.f) - mean*mean;
    mrs[t] = mean; rrs[t] = rsqrtf(fmaxf(var, 0.f) + kEps);
  }
  __syncthreads();
  if (tid < 192) {
    const int t = tid >> 2, grp = tid & 3;
    const float mean = mrs[t], rs = rrs[t];
    const size_t base = (((size_t)b*kN + n)*kT + t)*kD + grp*16;
    const float* xp = x + (size_t)b*(kD*kN*kT) + (size_t)n*kT + t;
    #pragma unroll
    for (int i4 = 0; i4 < 4; ++i4) {
      float4 o;
      float* op = (float*)&o;
      #pragma unroll
      for (int e = 0; e < 4; ++e) {
        const int d = grp*16 + i4*4 + e;
        const float tout = qs[d*48 + t];
        const float xv = xp[(size_t)d * (kN*kT)];
        op[e] = xv + (tout - mean)*rs*g0[d] + beta0[d];
      }
      *(float4*)(hout + base + i4*4) = o;
    }
  }
}

// ---------------- Kernel 2: spatial GCN — pre-swizzled adj, no-RMW epilogue ----------------
// 768 blocks x 512 thr; LDS 47.1 KB -> 3 blocks/CU. adjP reads: one full 128B line per
// wave instruction (zero over-fetch). h read from hsrc (ws when split), written to hdst
// (d_out) as pure full-line stores; hsrc==hdst falls back to in-place RMW.
__global__ __launch_bounds__(512, 6) void k2_spatial_mfma(
    const float* __restrict__ hsrc, float* __restrict__ hdst,
    const u16t* __restrict__ adjP, const u16t* __restrict__ ws,
    const float* __restrict__ g1, const float* __restrict__ beta1)
{
  __shared__ __align__(16) u16t Hs[208*64];
  __shared__ __align__(16) u16t Wb[32*224];          // overlaid by sout[32][68] fp32 in epilogue
  __shared__ __align__(16) u16t A2[32*64];
  __shared__ __align__(16) float rsumT[32][8];
  __shared__ float lnS[4][32], lnQ[4][32];

  const int tid = threadIdx.x;
  const int b = blockIdx.x / kT, t = blockIdx.x % kT;
  const int wv = tid >> 6, lane = tid & 63;
  const int c15 = lane & 15, quad = lane >> 4;
  const int dt = wv & 3, so = wv >> 2;          // owner d-tile / sub for agg,theta,LN
  const int nti = (wv < 5) ? 2 : 1;             // m-tiles: {wv} + {wv+8 if wv<5}
  const int dq = dt*16 + c15;

  const float g1f = g1[dq], be1f = beta1[dq];
  B8 bth[2];
  #pragma unroll
  for (int ksp = 0; ksp < 2; ++ksp)
    bth[ksp].i = *(const int4*)(ws + kThOff + dq*64 + ksp*32 + quad*8);

  // ---- stage H -> Hs (bf16, rot-swizzled); zero rows 200..207 ----
  for (int idx = tid; idx < kN*8; idx += 512) {
    const int n = idx >> 3, j = idx & 7;
    const float* src = hsrc + (((size_t)b*kN + n)*kT + t)*kD + j*8;
    const float4 p0 = *(const float4*)src, p1 = *(const float4*)(src + 4);
    B8 p;
    p.u[0]=f2bfu(p0.x); p.u[1]=f2bfu(p0.y); p.u[2]=f2bfu(p0.z); p.u[3]=f2bfu(p0.w);
    p.u[4]=f2bfu(p1.x); p.u[5]=f2bfu(p1.y); p.u[6]=f2bfu(p1.z); p.u[7]=f2bfu(p1.w);
    *(int4*)(Hs + n*64 + (((j + n) & 7) << 3)) = p.i;
  }
  if (tid < 64)
    *(int4*)(Hs + (200 + (tid >> 3))*64 + ((tid & 7) << 3)) = make_int4(0,0,0,0);
  for (int idx = tid; idx < (32*224)/8; idx += 512)
    *(int4*)(Wb + idx*8) = make_int4(0,0,0,0);
  __syncthreads();

  // ---- hoisted agg A-fragments: A[row=dq][k=m] = H[m][dq] ----
  B8 ahi[7];
  #pragma unroll
  for (int ksp = 0; ksp < 6; ++ksp) {
    #pragma unroll
    for (int j = 0; j < 8; ++j) {
      const int m = ksp*32 + quad*8 + j;
      ahi[ksp].u[j] = Hs[m*64 + ((((dq>>3) + m) & 7) << 3) + (dq & 7)];
    }
  }
  if (quad == 0) {
    #pragma unroll
    for (int j = 0; j < 8; ++j) {
      const int m = 192 + j;
      ahi[6].u[j] = Hs[m*64 + ((((dq>>3) + m) & 7) << 3) + (dq & 7)];
    }
  } else {
    ahi[6].i = make_int4(0, 0, 0, 0);
  }

  for (int cc = 0; cc < 7; ++cc) {
    const int n0 = cc * 32;
    const bool hasB = (cc < 6);
    const bool act = (so == 0) || hasB;
    const u16t* aPc = adjP + cc * kAdjPPerChunk;

    // ---- scores: this wave's m-tiles vs both row sub-blocks ----
    B8 afr0[2], afr1[2];
    #pragma unroll
    for (int ksp = 0; ksp < 2; ++ksp) {
      const int rowA = n0 + c15;
      afr0[ksp].i = *(const int4*)(Hs + rowA*64 + (((ksp*4 + quad + rowA) & 7) << 3));
      if (hasB) {
        const int rowB = rowA + 16;
        afr1[ksp].i = *(const int4*)(Hs + rowB*64 + (((ksp*4 + quad + rowB) & 7) << 3));
      } else afr1[ksp].i = make_int4(0,0,0,0);
    }
    f32x4 a00 = {0.f,0.f,0.f,0.f}, a01 = {0.f,0.f,0.f,0.f};
    f32x4 a10 = {0.f,0.f,0.f,0.f}, a11 = {0.f,0.f,0.f,0.f};
    #pragma unroll
    for (int ksp = 0; ksp < 2; ++ksp) {
      {
        const int row = wv*16 + c15;
        B8 bfr; bfr.i = *(const int4*)(Hs + row*64 + (((ksp*4 + quad + row) & 7) << 3));
        a00 = __builtin_amdgcn_mfma_f32_16x16x32_bf16(afr0[ksp].v, bfr.v, a00, 0, 0, 0);
        if (hasB) a10 = __builtin_amdgcn_mfma_f32_16x16x32_bf16(afr1[ksp].v, bfr.v, a10, 0, 0, 0);
      }
      if (nti == 2) {
        const int row = (wv + 8)*16 + c15;
        B8 bfr; bfr.i = *(const int4*)(Hs + row*64 + (((ksp*4 + quad + row) & 7) << 3));
        a01 = __builtin_amdgcn_mfma_f32_16x16x32_bf16(afr0[ksp].v, bfr.v, a01, 0, 0, 0);
        if (hasB) a11 = __builtin_amdgcn_mfma_f32_16x16x32_bf16(afr1[ksp].v, bfr.v, a11, 0, 0, 0);
      }
    }
    // no-max exp + per-wave row-sum partials
    float p00[4], p01[4], p10[4], p11[4], smr0[4], smr1[4];
    #pragma unroll
    for (int r = 0; r < 4; ++r) {
      p00[r] = __expf(fmaf(a00[r], 0.125f, -20.f));
      p01[r] = (nti == 2) ? __expf(fmaf(a01[r], 0.125f, -20.f)) : 0.f;
      smr0[r] = p00[r] + p01[r];
      p10[r] = hasB ? __expf(fmaf(a10[r], 0.125f, -20.f)) : 0.f;
      p11[r] = (hasB && nti == 2) ? __expf(fmaf(a11[r], 0.125f, -20.f)) : 0.f;
      smr1[r] = p10[r] + p11[r];
    }
    #pragma unroll
    for (int off = 1; off <= 8; off <<= 1)
      #pragma unroll
      for (int r = 0; r < 4; ++r) {
        smr0[r] += __shfl_xor(smr0[r], off, 64);
        smr1[r] += __shfl_xor(smr1[r], off, 64);
      }
    if (c15 == 0) {
      #pragma unroll
      for (int r = 0; r < 4; ++r) rsumT[quad*4 + r][wv] = smr0[r];
      if (hasB) {
        #pragma unroll
        for (int r = 0; r < 4; ++r) rsumT[16 + quad*4 + r][wv] = smr1[r];
      }
    }
    __syncthreads();

    // ---- Wb fill (adjP: one full line per wave instruction) ----
    // Re-zero the 2 per-row padding groups the sout overlay may have clobbered
    // (read by agg MFMA against a zero A-frag; NaN/Inf would poison it).
    if (tid < 64) {
      const int row = tid >> 1;
      int g = row + 26 + (tid & 1);
      if (g >= 28) g -= 28;
      if (g >= 28) g -= 28;
      *(int4*)(Wb + row*224 + g*8) = make_int4(0,0,0,0);
    }
    #pragma unroll
    for (int sub = 0; sub < 2; ++sub) {
      if (sub == 1 && !hasB) break;
      #pragma unroll
      for (int r = 0; r < 4; ++r) {
        const int RR = sub*16 + quad*4 + r;
        const float4 s0 = *(const float4*)&rsumT[RR][0];
        const float4 s1 = *(const float4*)&rsumT[RR][4];
        const float tot = ((s0.x + s0.y) + (s0.z + s0.w)) + ((s1.x + s1.y) + (s1.z + s1.w));
        const float inv = __fdividef(0.125f, fmaxf(tot, 1e-30f));
        {
          const float av = bfu2f(aPc[(wv*2 + sub)*256 + r*64 + lane]);
          const float pv = sub ? p10[r] : p00[r];
          const float w = pv * inv * av;
          int g = wv*2 + (c15 >> 3) + RR;
          if (g >= 28) g -= 28;
          Wb[RR*224 + g*8 + (c15 & 7)] = f2bfu(w);
        }
        if (nti == 2) {
          const float av = bfu2f(aPc[((wv + 8)*2 + sub)*256 + r*64 + lane]);
          const float pv = sub ? p11[r] : p01[r];
          const float w = pv * inv * av;
          int g = (wv + 8)*2 + (c15 >> 3) + RR;
          if (g >= 28) g -= 28;
          if (g >= 28) g -= 28;
          Wb[RR*224 + g*8 + (c15 & 7)] = f2bfu(w);
        }
      }
    }
    __syncthreads();

    // ---- agg: one (sub, d-tile) per wave; 4+3 split chains ----
    float vr[4];
    if (act) {
      const int RRr = so*16 + c15;
      f32x4 ag0 = {0.f,0.f,0.f,0.f}, ag1 = {0.f,0.f,0.f,0.f};
      #pragma unroll
      for (int ksp = 0; ksp < 7; ++ksp) {
        int g = ksp*4 + quad + RRr;
        if (g >= 28) g -= 28;
        if (g >= 28) g -= 28;
        B8 bw; bw.i = *(const int4*)(Wb + RRr*224 + g*8);
        if (ksp & 1) ag1 = __builtin_amdgcn_mfma_f32_16x16x32_bf16(ahi[ksp].v, bw.v, ag1, 0, 0, 0);
        else         ag0 = __builtin_amdgcn_mfma_f32_16x16x32_bf16(ahi[ksp].v, bw.v, ag0, 0, 0, 0);
      }
      #pragma unroll
      for (int r = 0; r < 4; ++r) {
        const int d = dt*16 + quad*4 + r;
        A2[RRr*64 + ((((d>>3) + RRr) & 7) << 3) + (d & 7)] = f2bfu(ag0[r] + ag1[r]);
      }
    }
    __syncthreads();

    // ---- theta + relu + LN partials ----
    if (act) {
      const int R = so*16 + c15;
      f32x4 o = {0.f,0.f,0.f,0.f};
      #pragma unroll
      for (int ksp = 0; ksp < 2; ++ksp) {
        B8 a; a.i = *(const int4*)(A2 + R*64 + (((ksp*4 + quad + R) & 7) << 3));
        o = __builtin_amdgcn_mfma_f32_16x16x32_bf16(a.v, bth[ksp].v, o, 0, 0, 0);
      }
      float ps[4], pq[4];
      #pragma unroll
      for (int r = 0; r < 4; ++r) {
        vr[r] = fmaxf(o[r], 0.f);
        ps[r] = vr[r]; pq[r] = vr[r]*vr[r];
      }
      #pragma unroll
      for (int off = 1; off <= 8; off <<= 1)
        #pragma unroll
        for (int r = 0; r < 4; ++r) {
          ps[r] += __shfl_xor(ps[r], off, 64);
          pq[r] += __shfl_xor(pq[r], off, 64);
        }
      if (c15 == 0) {
        #pragma unroll
        for (int r = 0; r < 4; ++r) {
          lnS[dt][so*16 + quad*4 + r] = ps[r];
          lnQ[dt][so*16 + quad*4 + r] = pq[r];
        }
      }
    }
    __syncthreads();

    // ---- finalize LN -> sout LDS tile (overlay on dead Wb), then coalesced write ----
    float* soutL = reinterpret_cast<float*>(Wb);    // [32][68] fp32 = 8704 B < 14336 B
    if (act) {
      #pragma unroll
      for (int r = 0; r < 4; ++r) {
        const int RR = so*16 + quad*4 + r;
        const float S = lnS[0][RR] + lnS[1][RR] + lnS[2][RR] + lnS[3][RR];
        const float Q = lnQ[0][RR] + lnQ[1][RR] + lnQ[2][RR] + lnQ[3][RR];
        const float mean = S * (1.f/64.f);
        const float var = Q * (1.f/64.f) - mean*mean;
        const float rs = rsqrtf(fmaxf(var, 0.f) + kEps);
        soutL[RR*68 + dq] = (vr[r] - mean)*rs*g1f + be1f;
      }
    }
    __syncthreads();
    {
      const int row = tid >> 4, c4v = tid & 15;     // 32 rows x 16 float4 = 512 threads
      const int n = n0 + row;
      if (n < kN) {
        const float4 sv = *(const float4*)&soutL[row*68 + c4v*4];
        const size_t off = (((size_t)b*kN + n)*kT + t)*kD + c4v*4;
        float4 hv = *(const float4*)(hsrc + off);
        hv.x += sv.x; hv.y += sv.y; hv.z += sv.z; hv.w += sv.w;
        *(float4*)(hdst + off) = hv;
      }
    }
    __syncthreads();   // protect soutL (=Wb) before next chunk's Wb fill
  }
}

} // namespace

extern "C" void kernel_launch(void* const* d_in, const int* in_sizes, int n_in,
                              void* d_out, int out_size, void* d_ws, size_t ws_size,
                              hipStream_t stream) {
  const float* x     = (const float*)d_in[0];
  const float* adj   = (const float*)d_in[1];
  const float* Wq    = (const float*)d_in[2];
  const float* bq    = (const float*)d_in[3];
  const float* Wk    = (const float*)d_in[4];
  const float* bk    = (const float*)d_in[5];
  const float* W1    = (const float*)d_in[6];
  const float* b1    = (const float*)d_in[7];
  const float* W2    = (const float*)d_in[8];
  const float* b2    = (const float*)d_in[9];
  const float* Theta = (const float*)d_in[10];
  const float* g0    = (const float*)d_in[11];
  const float* beta0 = (const float*)d_in[12];
  const float* g1    = (const float*)d_in[13];
  const float* beta1 = (const float*)d_in[14];

  u16t* wsb = (u16t*)d_ws;           // bf16 weight + swizzled-adj cache

  // Stage h in d_ws when it fits -> k2 does pure writes to d_out (no RMW).
  const bool split = ws_size >= kHOffBytes + kHBytes;
  float* hbuf = split ? (float*)((char*)d_ws + kHOffBytes) : (float*)d_out;

  k0_prep<<<dim3(48), dim3(256), 0, stream>>>(Wq, Wk, W1, W2, Theta, adj, wsb);
  k1_temporal<<<dim3(kB*kN), dim3(256), 0, stream>>>(
      x, wsb, bq, bk, b1, b2, g0, beta0, hbuf);
  k2_spatial_mfma<<<dim3(kB*kT), dim3(512), 0, stream>>>(
      hbuf, (float*)d_out, wsb + kAdjPOff, wsb, g1, beta1);
}

// Round 12
// 256.666 us; speedup vs baseline: 1.2587x; 1.2260x over previous
//
#include <hip/hip_runtime.h>
#include <hip/hip_bf16.h>

typedef unsigned short u16t;

namespace {

constexpr int kB = 16, kD = 64, kN = 200, kT = 48, kH = 8;
constexpr float kEps = 1e-5f;

typedef __attribute__((ext_vector_type(8))) __bf16 bf16x8;
typedef __attribute__((ext_vector_type(4))) float f32x4;
union B8 { int4 i; bf16x8 v; u16t u[8]; };

__device__ __forceinline__ u16t f2bfu(float f) {
  union { __hip_bfloat16 h; u16t u; } c; c.h = __float2bfloat16(f); return c.u;
}
__device__ __forceinline__ unsigned pk2(float a, float b) {
  return (unsigned)f2bfu(a) | ((unsigned)f2bfu(b) << 16);
}

// ---- workspace layout (u16 units) ----
constexpr int kWqOff = 0;
constexpr int kWkOff = 12288;
constexpr int kW1Off = 24576;
constexpr int kW2Off = 28672;
constexpr int kThOff = 32768;
constexpr size_t kWsWeightBytes = 73728;           // 36864 u16
constexpr size_t kHBytes = (size_t)kB * kN * kT * kD * 4;   // 39,321,600

// ---------------- Kernel 0: one-time weight bf16 pre-conversion ----------------
__global__ void k0_prep(const float* __restrict__ Wq, const float* __restrict__ Wk,
                        const float* __restrict__ W1, const float* __restrict__ W2,
                        const float* __restrict__ Theta, u16t* __restrict__ ws) {
  const int tid = blockIdx.x * 256 + threadIdx.x;
  const int stride = gridDim.x * 256;
  for (int idx = tid; idx < 64 * 192; idx += stride) {
    const int row = idx / 192, rem = idx % 192;
    const int tap = rem >> 6, c = rem & 63;
    const int src = row * 192 + c * 3 + tap;   // Wq layout (D_out, D_in, 1, 3)
    ws[kWqOff + idx] = f2bfu(Wq[src]);
    ws[kWkOff + idx] = f2bfu(Wk[src]);
  }
  for (int idx = tid; idx < 4096; idx += stride) {
    ws[kW1Off + idx] = f2bfu(W1[idx]);
    ws[kW2Off + idx] = f2bfu(W2[idx]);
    ws[kThOff + idx] = f2bfu(Theta[idx]);
  }
}

// ---------------- Kernel 1: temporal attention, fully MFMA (R5-proven) ----------------
__global__ __launch_bounds__(256, 4) void k1_temporal(
    const float* __restrict__ x, const u16t* __restrict__ ws,
    const float* __restrict__ bq, const float* __restrict__ bk,
    const float* __restrict__ b1, const float* __restrict__ b2,
    const float* __restrict__ g0, const float* __restrict__ beta0,
    float* __restrict__ hout)
{
  __shared__ __align__(16) float qs[3072];       // W2 out (LN input) [64][48]
  __shared__ __align__(16) u16t lds_h[13440];
  u16t* XT  = lds_h;            // [50][64]: elem(r,d) at r*64 + ((d/8 + r)&7)*8 + d%8 (rows 0,49 zero)
  u16t* osT = lds_h;            // overlay XT (dead after QKV): [48][64] same swizzle
  u16t* QT  = lds_h + 3200;     // [48][64]: elem(t,d) at t*64 + ((d/8 + t)&7)*8 + d%8
  u16t* KT  = lds_h + 6272;     // same layout
  u16t* VTT = lds_h + 9344;     // [64][64]: elem(d,s) at d*64 + ((s/8 + d)&7)*8 + s%8 (cols 48..63 zero)

  const int tid = threadIdx.x;
  const int b = blockIdx.x / kN, n = blockIdx.x % kN;
  const int wv = tid >> 6, lane = tid & 63;
  const int c15 = lane & 15, quad = lane >> 4;

  // ---- stage x[b,:,n,:] -> XT; zero-pad VTT cols 48..63 ----
  if (tid < 192) {
    const int dp = tid & 31, j = tid >> 5;
    const int d0 = dp * 2;
    const size_t xi = (size_t)b * (kD*kN*kT) + (size_t)d0 * (kN*kT) + (size_t)n * kT + j * 8;
    const float4 a0 = *(const float4*)(x + xi);
    const float4 a1 = *(const float4*)(x + xi + 4);
    const float4 c0 = *(const float4*)(x + xi + kN*kT);
    const float4 c1 = *(const float4*)(x + xi + kN*kT + 4);
    float f0[8] = {a0.x,a0.y,a0.z,a0.w,a1.x,a1.y,a1.z,a1.w};
    float f1[8] = {c0.x,c0.y,c0.z,c0.w,c1.x,c1.y,c1.z,c1.w};
    u16t* bb = XT + (d0 & 7);
    const int blk = d0 >> 3;
    #pragma unroll
    for (int e = 0; e < 8; ++e) {
      const int r = j*8 + e + 1;                 // row = t+1
      const unsigned pkd = (unsigned)f2bfu(f0[e]) | ((unsigned)f2bfu(f1[e]) << 16);
      *(unsigned*)(bb + r*64 + ((blk + r) & 7) * 8) = pkd;
    }
  } else if (tid < 208) {                        // XT rows 0 and 49 := 0
    const int g = tid - 192;
    const int rr = (g >> 3) ? 49 : 0, gg = g & 7;
    *(int4*)(XT + rr*64 + gg*8) = make_int4(0,0,0,0);
  }
  if (tid < 128) {                               // VTT cols 48..63 := 0
    const int d = tid >> 1, g = tid & 1;
    *(int4*)(VTT + d*64 + (((6 + g + d) & 7) << 3)) = make_int4(0,0,0,0);
  }
  __syncthreads();

  // ---- QKV via MFMA -> bf16 LDS (QT/KT/VTT) ----
  {
    const int dqr = wv*16 + c15;
    B8 aq[6], ak[6], av2[2];
    #pragma unroll
    for (int tap = 0; tap < 3; ++tap)
      #pragma unroll
      for (int ksp = 0; ksp < 2; ++ksp) {
        const int off = dqr*192 + tap*64 + ksp*32 + quad*8;
        aq[tap*2+ksp].i = *(const int4*)(ws + kWqOff + off);
        ak[tap*2+ksp].i = *(const int4*)(ws + kWkOff + off);
      }
    #pragma unroll
    for (int ksp = 0; ksp < 2; ++ksp)
      av2[ksp].i = *(const int4*)(ws + kW1Off + dqr*64 + ksp*32 + quad*8);
    float bqv[4], bkv[4], b1v[4];
    #pragma unroll
    for (int r = 0; r < 4; ++r) {
      const int row = wv*16 + quad*4 + r;
      bqv[r] = bq[row]; bkv[r] = bk[row]; b1v[r] = b1[row];
    }
    const int dbase = wv*16 + quad*4;
    const int dblk = dbase >> 3;
    constexpr float kScale = 0.35355339059327373f;  // 1/sqrt(DK), folded into Q

    for (int i = 0; i < 3; ++i) {
      const int t0 = i * 16;
      B8 bf[3][2];
      #pragma unroll
      for (int tap = 0; tap < 3; ++tap)
        #pragma unroll
        for (int ksp = 0; ksp < 2; ++ksp) {
          const int r = t0 + c15 + tap;
          bf[tap][ksp].i = *(const int4*)(XT + r*64 + (((ksp*4 + quad) + r) & 7)*8);
        }
      f32x4 accq = {0.f,0.f,0.f,0.f}, acck = {0.f,0.f,0.f,0.f}, accv = {0.f,0.f,0.f,0.f};
      #pragma unroll
      for (int tap = 0; tap < 3; ++tap)
        #pragma unroll
        for (int ksp = 0; ksp < 2; ++ksp) {
          accq = __builtin_amdgcn_mfma_f32_16x16x32_bf16(aq[tap*2+ksp].v, bf[tap][ksp].v, accq, 0, 0, 0);
          acck = __builtin_amdgcn_mfma_f32_16x16x32_bf16(ak[tap*2+ksp].v, bf[tap][ksp].v, acck, 0, 0, 0);
        }
      #pragma unroll
      for (int ksp = 0; ksp < 2; ++ksp)
        accv = __builtin_amdgcn_mfma_f32_16x16x32_bf16(av2[ksp].v, bf[1][ksp].v, accv, 0, 0, 0);

      const int t = t0 + c15;
      const int rotq = (dblk + t) & 7;
      const unsigned q01 = pk2((accq[0]+bqv[0])*kScale, (accq[1]+bqv[1])*kScale);
      const unsigned q23 = pk2((accq[2]+bqv[2])*kScale, (accq[3]+bqv[3])*kScale);
      *(int2*)(QT + t*64 + rotq*8 + (quad&1)*4) = make_int2((int)q01, (int)q23);
      const unsigned k01 = pk2(acck[0]+bkv[0], acck[1]+bkv[1]);
      const unsigned k23 = pk2(acck[2]+bkv[2], acck[3]+bkv[3]);
      *(int2*)(KT + t*64 + rotq*8 + (quad&1)*4) = make_int2((int)k01, (int)k23);
      #pragma unroll
      for (int r = 0; r < 4; ++r) {
        const int d = dbase + r;
        VTT[d*64 + ((((t>>3) + d) & 7) << 3) + (t & 7)] = f2bfu(accv[r] + b1v[r]);
      }
    }
  }
  __syncthreads();   // also protects XT reads before osT overlay writes

  // ---- attention via MFMA: wave wv handles heads 2wv, 2wv+1 (no-max softmax) ----
  #pragma unroll
  for (int hh = 0; hh < 2; ++hh) {
    const int h = wv*2 + hh;
    B8 vb[2];
    #pragma unroll
    for (int ksp = 0; ksp < 2; ++ksp) {
      if (c15 < 8) {
        const int dr = h*8 + c15;
        vb[ksp].i = *(const int4*)(VTT + dr*64 + (((ksp*4 + quad + dr) & 7) << 3));
      } else vb[ksp].i = make_int4(0,0,0,0);
    }
    #pragma unroll
    for (int nt = 0; nt < 3; ++nt) {
      B8 qb;
      if (quad == 0) {
        const int t = nt*16 + c15;
        qb.i = *(const int4*)(QT + t*64 + (((h + t) & 7) << 3));
      } else qb.i = make_int4(0,0,0,0);
      f32x4 sa[3];
      #pragma unroll
      for (int ms = 0; ms < 3; ++ms) {
        B8 ka;
        if (quad == 0) {
          const int s = ms*16 + c15;
          ka.i = *(const int4*)(KT + s*64 + (((h + s) & 7) << 3));
        } else ka.i = make_int4(0,0,0,0);
        f32x4 z = {0.f,0.f,0.f,0.f};
        sa[ms] = __builtin_amdgcn_mfma_f32_16x16x32_bf16(ka.v, qb.v, z, 0, 0, 0);
      }
      // no-max softmax: scores bounded, exp(s) safe in fp32
      float p[3][4]; float es = 0.f;
      #pragma unroll
      for (int ms = 0; ms < 3; ++ms)
        #pragma unroll
        for (int r = 0; r < 4; ++r) { p[ms][r] = __expf(sa[ms][r]); es += p[ms][r]; }
      es += __shfl_xor(es, 16, 64);
      es += __shfl_xor(es, 32, 64);
      const float inv = __fdividef(1.f, es);
      unsigned pkk[3][2];
      #pragma unroll
      for (int ms = 0; ms < 3; ++ms) {
        pkk[ms][0] = pk2(p[ms][0]*inv, p[ms][1]*inv);
        pkk[ms][1] = pk2(p[ms][2]*inv, p[ms][3]*inv);
      }
      // redistribute P -> PV A-frags (in-register, same-wave shfl)
      const int srcA = c15 + ((2*(quad & 1)) << 4);
      const int srcB = srcA + 16;
      const unsigned w0A = __shfl((int)pkk[0][0], srcA, 64), w0B = __shfl((int)pkk[1][0], srcA, 64);
      const unsigned w1A = __shfl((int)pkk[0][1], srcA, 64), w1B = __shfl((int)pkk[1][1], srcA, 64);
      const unsigned w2A = __shfl((int)pkk[0][0], srcB, 64), w2B = __shfl((int)pkk[1][0], srcB, 64);
      const unsigned w3A = __shfl((int)pkk[0][1], srcB, 64), w3B = __shfl((int)pkk[1][1], srcB, 64);
      const bool hi = quad >= 2;
      B8 a0;
      a0.i = make_int4((int)(hi ? w0B : w0A), (int)(hi ? w1B : w1A),
                       (int)(hi ? w2B : w2A), (int)(hi ? w3B : w3A));
      const int srcC = (c15 + ((2*quad) << 4)) & 63;
      const int srcD = (srcC + 16) & 63;
      const unsigned y0 = __shfl((int)pkk[2][0], srcC, 64), y1 = __shfl((int)pkk[2][1], srcC, 64);
      const unsigned y2 = __shfl((int)pkk[2][0], srcD, 64), y3 = __shfl((int)pkk[2][1], srcD, 64);
      B8 a1;
      if (quad < 2) a1.i = make_int4((int)y0, (int)y1, (int)y2, (int)y3);
      else          a1.i = make_int4(0,0,0,0);
      // PV
      f32x4 ov = {0.f,0.f,0.f,0.f};
      ov = __builtin_amdgcn_mfma_f32_16x16x32_bf16(a0.v, vb[0].v, ov, 0, 0, 0);
      ov = __builtin_amdgcn_mfma_f32_16x16x32_bf16(a1.v, vb[1].v, ov, 0, 0, 0);
      if (c15 < 8) {
        #pragma unroll
        for (int r = 0; r < 4; ++r) {
          const int t = nt*16 + quad*4 + r;
          osT[t*64 + (((h + t) & 7) << 3) + c15] = f2bfu(ov[r]);
        }
      }
    }
  }
  __syncthreads();

  // ---- W2 projection via MFMA -> qs ----
  {
    const int dqr = wv*16 + c15;
    B8 a2[2];
    #pragma unroll
    for (int ksp = 0; ksp < 2; ++ksp)
      a2[ksp].i = *(const int4*)(ws + kW2Off + dqr*64 + ksp*32 + quad*8);
    float b2v[4];
    #pragma unroll
    for (int r = 0; r < 4; ++r) b2v[r] = b2[wv*16 + quad*4 + r];
    for (int i = 0; i < 3; ++i) {
      const int t0 = i * 16;
      f32x4 acc = {0.f,0.f,0.f,0.f};
      #pragma unroll
      for (int ksp = 0; ksp < 2; ++ksp) {
        const int r = t0 + c15;
        B8 bo; bo.i = *(const int4*)(osT + r*64 + (((ksp*4 + quad) + r) & 7)*8);
        acc = __builtin_amdgcn_mfma_f32_16x16x32_bf16(a2[ksp].v, bo.v, acc, 0, 0, 0);
      }
      #pragma unroll
      for (int r = 0; r < 4; ++r)
        qs[(wv*16 + quad*4 + r)*48 + t0 + c15] = acc[r] + b2v[r];
    }
  }
  __syncthreads();

  // ---- LayerNorm + residual (scratch overlays dead XT/osT region) ----
  float* redm = reinterpret_cast<float*>(lds_h);      // [48][4]
  float* redv = redm + 192;                           // [48][4]
  float* mrs  = redm + 384;                           // [48]
  float* rrs  = redm + 432;                           // [48]
  if (tid < 192) {
    const int t = tid >> 2, grp = tid & 3;
    float sm = 0.f, sq = 0.f;
    #pragma unroll
    for (int i = 0; i < 16; ++i) {
      const float v = qs[(grp*16+i)*48 + t];
      sm += v; sq += v*v;
    }
    redm[t*4+grp] = sm; redv[t*4+grp] = sq;
  }
  __syncthreads();
  if (tid < 48) {
    const int t = tid;
    const float sm = redm[t*4] + redm[t*4+1] + redm[t*4+2] + redm[t*4+3];
    const float sq = redv[t*4] + redv[t*4+1] + redv[t*4+2] + redv[t*4+3];
    const float mean = sm * (1.f/64.f);
    const float var = sq * (1.f/64.f) - mean*mean;
    mrs[t] = mean; rrs[t] = rsqrtf(fmaxf(var, 0.f) + kEps);
  }
  __syncthreads();
  if (tid < 192) {
    const int t = tid >> 2, grp = tid & 3;
    const float mean = mrs[t], rs = rrs[t];
    const size_t base = (((size_t)b*kN + n)*kT + t)*kD + grp*16;
    const float* xp = x + (size_t)b*(kD*kN*kT) + (size_t)n*kT + t;
    #pragma unroll
    for (int i4 = 0; i4 < 4; ++i4) {
      float4 o;
      float* op = (float*)&o;
      #pragma unroll
      for (int e = 0; e < 4; ++e) {
        const int d = grp*16 + i4*4 + e;
        const float tout = qs[d*48 + t];
        const float xv = xp[(size_t)d * (kN*kT)];
        op[e] = xv + (tout - mean)*rs*g0[d] + beta0[d];
      }
      *(float4*)(hout + base + i4*4) = o;
    }
  }
}

// ---------------- Kernel 2: spatial GCN — R3 structure + no-max softmax ----------------
// 4 waves / 256 thr, LDS 36,864 -> 4 blocks/CU. Optional 2-way rb-split per (b,t)
// (h staged in ws -> no in-place race). Scalar RMW epilogue (R3-proven: 138 µs).
__global__ __launch_bounds__(256, 4) void k2_spatial_mfma(
    const float* __restrict__ hsrc, float* __restrict__ hdst,
    const float* __restrict__ adj, const u16t* __restrict__ ws,
    const float* __restrict__ g1, const float* __restrict__ beta1, int nparts)
{
  __shared__ __align__(16) u16t Hs[208*64];
  __shared__ __align__(16) u16t Wb[16*224];
  __shared__ __align__(16) u16t A2[16*64];
  __shared__ float rsum[4][16], lnS[4][16], lnQ[4][16];

  const int tid = threadIdx.x;
  int bt, part;
  if (nparts == 2) { bt = blockIdx.x >> 1; part = blockIdx.x & 1; }
  else             { bt = blockIdx.x;      part = 0; }
  const int b = bt / kT, t = bt % kT;
  const int rbBeg = (part == 0) ? 0 : 7;
  const int rbEnd = (nparts == 2 && part == 0) ? 7 : 13;
  const int wv = tid >> 6, lane = tid & 63;
  const int c15 = lane & 15, quad = lane >> 4;
  const int myf = wv*16 + c15;

  const float g1f = g1[myf], be1f = beta1[myf];

  B8 bth[2];
  #pragma unroll
  for (int ksp = 0; ksp < 2; ++ksp)
    bth[ksp].i = *(const int4*)(ws + kThOff + myf*64 + ksp*32 + quad*8);

  // ---- stage H -> Hs (bf16, rot-swizzled); zero rows 200..207; zero Wb ----
  for (int idx = tid; idx < kN*8; idx += 256) {
    const int n = idx >> 3, j = idx & 7;
    const float* src = hsrc + (((size_t)b*kN + n)*kT + t)*kD + j*8;
    const float4 p0 = *(const float4*)src, p1 = *(const float4*)(src + 4);
    B8 p;
    p.u[0]=f2bfu(p0.x); p.u[1]=f2bfu(p0.y); p.u[2]=f2bfu(p0.z); p.u[3]=f2bfu(p0.w);
    p.u[4]=f2bfu(p1.x); p.u[5]=f2bfu(p1.y); p.u[6]=f2bfu(p1.z); p.u[7]=f2bfu(p1.w);
    *(int4*)(Hs + n*64 + (((j + n) & 7) << 3)) = p.i;
  }
  if (tid < 64) {
    *(int4*)(Hs + (200 + (tid >> 3))*64 + ((tid & 7) << 3)) = make_int4(0,0,0,0);
  }
  for (int idx = tid; idx < (16*224)/8; idx += 256)
    *(int4*)(Wb + idx*8) = make_int4(0,0,0,0);
  __syncthreads();

  // ---- hoisted agg A-fragments: A[row=dA][k=m] = H[m][dA], rb-invariant ----
  const int dA = wv*16 + c15;
  B8 ahi[7];
  #pragma unroll
  for (int ksp = 0; ksp < 6; ++ksp) {
    const int m0 = ksp*32 + quad*8;
    #pragma unroll
    for (int j = 0; j < 8; ++j) {
      const int m = m0 + j;
      ahi[ksp].u[j] = Hs[m*64 + ((((dA>>3) + m) & 7) << 3) + (dA & 7)];
    }
  }
  if (quad == 0) {
    #pragma unroll
    for (int j = 0; j < 8; ++j) {
      const int m = 192 + j;
      ahi[6].u[j] = Hs[m*64 + ((((dA>>3) + m) & 7) << 3) + (dA & 7)];
    }
  } else {
    ahi[6].i = make_int4(0, 0, 0, 0);
  }

  for (int rb = rbBeg; rb < rbEnd; ++rb) {
    const int n0 = rb * 16;

    B8 afr[2];
    #pragma unroll
    for (int ksp = 0; ksp < 2; ++ksp) {
      const int row = n0 + c15;
      afr[ksp].i = *(const int4*)(Hs + row*64 + (((ksp*4 + quad + row) & 7) << 3));
    }
    f32x4 cs[3];
    #pragma unroll
    for (int i = 0; i < 3; ++i) {
      const int mt = wv + 4*i;
      f32x4 acc = {0.f, 0.f, 0.f, 0.f};
      #pragma unroll
      for (int ksp = 0; ksp < 2; ++ksp) {
        const int row = mt*16 + c15;
        B8 bfr; bfr.i = *(const int4*)(Hs + row*64 + (((ksp*4 + quad + row) & 7) << 3));
        acc = __builtin_amdgcn_mfma_f32_16x16x32_bf16(afr[ksp].v, bfr.v, acc, 0, 0, 0);
      }
      cs[i] = acc;
    }
    const bool has4 = (wv == 0);
    f32x4 cs3 = {0.f, 0.f, 0.f, 0.f};
    if (has4) {
      #pragma unroll
      for (int ksp = 0; ksp < 2; ++ksp) {
        const int row = 192 + c15;
        B8 bfr; bfr.i = *(const int4*)(Hs + row*64 + (((ksp*4 + quad + row) & 7) << 3));
        cs3 = __builtin_amdgcn_mfma_f32_16x16x32_bf16(afr[ksp].v, bfr.v, cs3, 0, 0, 0);
      }
    }

    // ---- no-max softmax: p = exp(s/8 - 20); shift cancels in p/sum. One barrier. ----
    float smr[4];
    #pragma unroll
    for (int r = 0; r < 4; ++r) {
      cs[0][r] = __expf(fmaf(cs[0][r], 0.125f, -20.f));
      cs[1][r] = __expf(fmaf(cs[1][r], 0.125f, -20.f));
      cs[2][r] = __expf(fmaf(cs[2][r], 0.125f, -20.f));
      cs3[r]   = (has4 && c15 < 8) ? __expf(fmaf(cs3[r], 0.125f, -20.f)) : 0.f;
      smr[r] = cs[0][r] + cs[1][r] + cs[2][r] + cs3[r];
    }
    #pragma unroll
    for (int off = 1; off <= 8; off <<= 1)
      #pragma unroll
      for (int r = 0; r < 4; ++r) smr[r] += __shfl_xor(smr[r], off, 64);
    if (c15 == 0) {
      #pragma unroll
      for (int r = 0; r < 4; ++r) rsum[wv][quad*4 + r] = smr[r];
    }
    __syncthreads();
    #pragma unroll
    for (int r = 0; r < 4; ++r) {
      const int rr = quad*4 + r;
      const float tot = rsum[0][rr] + rsum[1][rr] + rsum[2][rr] + rsum[3][rr];
      const float inv = __fdividef(0.125f, fmaxf(tot, 1e-30f));
      const int n = n0 + rr;
      const bool vrow = (n < kN);
      const int na = vrow ? n : (kN - 1);
      #pragma unroll
      for (int i = 0; i < 3; ++i) {
        const int m = (wv + 4*i)*16 + c15;
        const float w = vrow ? cs[i][r] * inv * adj[(size_t)na*kN + m] : 0.f;
        Wb[rr*224 + (((m >> 3) + rr) % 28)*8 + (m & 7)] = f2bfu(w);
      }
      if (has4 && c15 < 8) {
        const int m = 192 + c15;
        const float w = vrow ? cs3[r] * inv * adj[(size_t)na*kN + m] : 0.f;
        Wb[rr*224 + (((m >> 3) + rr) % 28)*8 + (m & 7)] = f2bfu(w);
      }
    }
    __syncthreads();

    // ---- agg: A from hoisted registers, B from Wb ----
    f32x4 ag = {0.f, 0.f, 0.f, 0.f};
    #pragma unroll
    for (int ksp = 0; ksp < 7; ++ksp) {
      B8 bw; bw.i = *(const int4*)(Wb + c15*224 + ((ksp*4 + quad + c15) % 28)*8);
      ag = __builtin_amdgcn_mfma_f32_16x16x32_bf16(ahi[ksp].v, bw.v, ag, 0, 0, 0);
    }
    {
      const int dbase = wv*16 + quad*4;
      #pragma unroll
      for (int r = 0; r < 4; ++r) {
        const int d = dbase + r;
        A2[c15*64 + (((d >> 3) + c15) & 7)*8 + (d & 7)] = f2bfu(ag[r]);
      }
    }
    __syncthreads();

    f32x4 o = {0.f, 0.f, 0.f, 0.f};
    #pragma unroll
    for (int ksp = 0; ksp < 2; ++ksp) {
      B8 a; a.i = *(const int4*)(A2 + c15*64 + (((ksp*4 + quad + c15) & 7) << 3));
      o = __builtin_amdgcn_mfma_f32_16x16x32_bf16(a.v, bth[ksp].v, o, 0, 0, 0);
    }
    float vr[4], ps[4], pq[4];
    #pragma unroll
    for (int r = 0; r < 4; ++r) {
      vr[r] = fmaxf(o[r], 0.f);
      ps[r] = vr[r]; pq[r] = vr[r]*vr[r];
    }
    #pragma unroll
    for (int off = 1; off <= 8; off <<= 1)
      #pragma unroll
      for (int r = 0; r < 4; ++r) {
        ps[r] += __shfl_xor(ps[r], off, 64);
        pq[r] += __shfl_xor(pq[r], off, 64);
      }
    if (c15 == 0) {
      #pragma unroll
      for (int r = 0; r < 4; ++r) { lnS[wv][quad*4+r] = ps[r]; lnQ[wv][quad*4+r] = pq[r]; }
    }
    __syncthreads();
    #pragma unroll
    for (int r = 0; r < 4; ++r) {
      const int rr = quad*4 + r, n = n0 + rr;
      const float S = lnS[0][rr] + lnS[1][rr] + lnS[2][rr] + lnS[3][rr];
      const float Q = lnQ[0][rr] + lnQ[1][rr] + lnQ[2][rr] + lnQ[3][rr];
      const float mean = S * (1.f/64.f);
      const float var = Q * (1.f/64.f) - mean*mean;
      const float rs = rsqrtf(fmaxf(var, 0.f) + kEps);
      if (n < kN) {
        const float sout = (vr[r] - mean)*rs*g1f + be1f;
        const size_t oi = (((size_t)b*kN + n)*kT + t)*kD + myf;
        hdst[oi] = hsrc[oi] + sout;
      }
    }
  }
}

} // namespace

extern "C" void kernel_launch(void* const* d_in, const int* in_sizes, int n_in,
                              void* d_out, int out_size, void* d_ws, size_t ws_size,
                              hipStream_t stream) {
  const float* x     = (const float*)d_in[0];
  const float* adj   = (const float*)d_in[1];
  const float* Wq    = (const float*)d_in[2];
  const float* bq    = (const float*)d_in[3];
  const float* Wk    = (const float*)d_in[4];
  const float* bk    = (const float*)d_in[5];
  const float* W1    = (const float*)d_in[6];
  const float* b1    = (const float*)d_in[7];
  const float* W2    = (const float*)d_in[8];
  const float* b2    = (const float*)d_in[9];
  const float* Theta = (const float*)d_in[10];
  const float* g0    = (const float*)d_in[11];
  const float* beta0 = (const float*)d_in[12];
  const float* g1    = (const float*)d_in[13];
  const float* beta1 = (const float*)d_in[14];

  u16t* wsb = (u16t*)d_ws;           // bf16 weight cache (73728 B)

  // If the workspace can hold h, stage h there and split k2 2-way per (b,t)
  // (avoids in-place read/write race between the two parts).
  const bool split = ws_size >= kWsWeightBytes + kHBytes;
  float* hbuf = split ? (float*)((char*)d_ws + kWsWeightBytes) : (float*)d_out;
  const int nparts = split ? 2 : 1;

  k0_prep<<<dim3(48), dim3(256), 0, stream>>>(Wq, Wk, W1, W2, Theta, wsb);
  k1_temporal<<<dim3(kB*kN), dim3(256), 0, stream>>>(
      x, wsb, bq, bk, b1, b2, g0, beta0, hbuf);
  k2_spatial_mfma<<<dim3(kB*kT*nparts), dim3(256), 0, stream>>>(
      hbuf, (float*)d_out, adj, wsb, g1, beta1, nparts);
}

// Round 13
// 251.174 us; speedup vs baseline: 1.2863x; 1.0219x over previous
//
#include <hip/hip_runtime.h>
#include <hip/hip_bf16.h>

typedef unsigned short u16t;

namespace {

constexpr int kB = 16, kD = 64, kN = 200, kT = 48, kH = 8;
constexpr float kEps = 1e-5f;

typedef __attribute__((ext_vector_type(8))) __bf16 bf16x8;
typedef __attribute__((ext_vector_type(4))) float f32x4;
union B8 { int4 i; bf16x8 v; u16t u[8]; };

__device__ __forceinline__ u16t f2bfu(float f) {
  union { __hip_bfloat16 h; u16t u; } c; c.h = __float2bfloat16(f); return c.u;
}
__device__ __forceinline__ unsigned pk2(float a, float b) {
  return (unsigned)f2bfu(a) | ((unsigned)f2bfu(b) << 16);
}

// ---- workspace layout (u16 units) ----
constexpr int kWqOff = 0;
constexpr int kWkOff = 12288;
constexpr int kW1Off = 24576;
constexpr int kW2Off = 28672;
constexpr int kThOff = 32768;
constexpr size_t kWsWeightBytes = 73728;           // 36864 u16
constexpr size_t kHBytes = (size_t)kB * kN * kT * kD * 4;   // 39,321,600

// ---------------- Kernel 0: one-time weight bf16 pre-conversion ----------------
__global__ void k0_prep(const float* __restrict__ Wq, const float* __restrict__ Wk,
                        const float* __restrict__ W1, const float* __restrict__ W2,
                        const float* __restrict__ Theta, u16t* __restrict__ ws) {
  const int tid = blockIdx.x * 256 + threadIdx.x;
  const int stride = gridDim.x * 256;
  for (int idx = tid; idx < 64 * 192; idx += stride) {
    const int row = idx / 192, rem = idx % 192;
    const int tap = rem >> 6, c = rem & 63;
    const int src = row * 192 + c * 3 + tap;   // Wq layout (D_out, D_in, 1, 3)
    ws[kWqOff + idx] = f2bfu(Wq[src]);
    ws[kWkOff + idx] = f2bfu(Wk[src]);
  }
  for (int idx = tid; idx < 4096; idx += stride) {
    ws[kW1Off + idx] = f2bfu(W1[idx]);
    ws[kW2Off + idx] = f2bfu(W2[idx]);
    ws[kThOff + idx] = f2bfu(Theta[idx]);
  }
}

// ---------------- Kernel 1: temporal attention, fully MFMA (R5-proven, unchanged) ----------------
__global__ __launch_bounds__(256, 4) void k1_temporal(
    const float* __restrict__ x, const u16t* __restrict__ ws,
    const float* __restrict__ bq, const float* __restrict__ bk,
    const float* __restrict__ b1, const float* __restrict__ b2,
    const float* __restrict__ g0, const float* __restrict__ beta0,
    float* __restrict__ hout)
{
  __shared__ __align__(16) float qs[3072];       // W2 out (LN input) [64][48]
  __shared__ __align__(16) u16t lds_h[13440];
  u16t* XT  = lds_h;            // [50][64]: elem(r,d) at r*64 + ((d/8 + r)&7)*8 + d%8 (rows 0,49 zero)
  u16t* osT = lds_h;            // overlay XT (dead after QKV): [48][64] same swizzle
  u16t* QT  = lds_h + 3200;     // [48][64]: elem(t,d) at t*64 + ((d/8 + t)&7)*8 + d%8
  u16t* KT  = lds_h + 6272;     // same layout
  u16t* VTT = lds_h + 9344;     // [64][64]: elem(d,s) at d*64 + ((s/8 + d)&7)*8 + s%8 (cols 48..63 zero)

  const int tid = threadIdx.x;
  const int b = blockIdx.x / kN, n = blockIdx.x % kN;
  const int wv = tid >> 6, lane = tid & 63;
  const int c15 = lane & 15, quad = lane >> 4;

  // ---- stage x[b,:,n,:] -> XT; zero-pad VTT cols 48..63 ----
  if (tid < 192) {
    const int dp = tid & 31, j = tid >> 5;
    const int d0 = dp * 2;
    const size_t xi = (size_t)b * (kD*kN*kT) + (size_t)d0 * (kN*kT) + (size_t)n * kT + j * 8;
    const float4 a0 = *(const float4*)(x + xi);
    const float4 a1 = *(const float4*)(x + xi + 4);
    const float4 c0 = *(const float4*)(x + xi + kN*kT);
    const float4 c1 = *(const float4*)(x + xi + kN*kT + 4);
    float f0[8] = {a0.x,a0.y,a0.z,a0.w,a1.x,a1.y,a1.z,a1.w};
    float f1[8] = {c0.x,c0.y,c0.z,c0.w,c1.x,c1.y,c1.z,c1.w};
    u16t* bb = XT + (d0 & 7);
    const int blk = d0 >> 3;
    #pragma unroll
    for (int e = 0; e < 8; ++e) {
      const int r = j*8 + e + 1;                 // row = t+1
      const unsigned pkd = (unsigned)f2bfu(f0[e]) | ((unsigned)f2bfu(f1[e]) << 16);
      *(unsigned*)(bb + r*64 + ((blk + r) & 7) * 8) = pkd;
    }
  } else if (tid < 208) {                        // XT rows 0 and 49 := 0
    const int g = tid - 192;
    const int rr = (g >> 3) ? 49 : 0, gg = g & 7;
    *(int4*)(XT + rr*64 + gg*8) = make_int4(0,0,0,0);
  }
  if (tid < 128) {                               // VTT cols 48..63 := 0
    const int d = tid >> 1, g = tid & 1;
    *(int4*)(VTT + d*64 + (((6 + g + d) & 7) << 3)) = make_int4(0,0,0,0);
  }
  __syncthreads();

  // ---- QKV via MFMA -> bf16 LDS (QT/KT/VTT) ----
  {
    const int dqr = wv*16 + c15;
    B8 aq[6], ak[6], av2[2];
    #pragma unroll
    for (int tap = 0; tap < 3; ++tap)
      #pragma unroll
      for (int ksp = 0; ksp < 2; ++ksp) {
        const int off = dqr*192 + tap*64 + ksp*32 + quad*8;
        aq[tap*2+ksp].i = *(const int4*)(ws + kWqOff + off);
        ak[tap*2+ksp].i = *(const int4*)(ws + kWkOff + off);
      }
    #pragma unroll
    for (int ksp = 0; ksp < 2; ++ksp)
      av2[ksp].i = *(const int4*)(ws + kW1Off + dqr*64 + ksp*32 + quad*8);
    float bqv[4], bkv[4], b1v[4];
    #pragma unroll
    for (int r = 0; r < 4; ++r) {
      const int row = wv*16 + quad*4 + r;
      bqv[r] = bq[row]; bkv[r] = bk[row]; b1v[r] = b1[row];
    }
    const int dbase = wv*16 + quad*4;
    const int dblk = dbase >> 3;
    constexpr float kScale = 0.35355339059327373f;  // 1/sqrt(DK), folded into Q

    for (int i = 0; i < 3; ++i) {
      const int t0 = i * 16;
      B8 bf[3][2];
      #pragma unroll
      for (int tap = 0; tap < 3; ++tap)
        #pragma unroll
        for (int ksp = 0; ksp < 2; ++ksp) {
          const int r = t0 + c15 + tap;
          bf[tap][ksp].i = *(const int4*)(XT + r*64 + (((ksp*4 + quad) + r) & 7)*8);
        }
      f32x4 accq = {0.f,0.f,0.f,0.f}, acck = {0.f,0.f,0.f,0.f}, accv = {0.f,0.f,0.f,0.f};
      #pragma unroll
      for (int tap = 0; tap < 3; ++tap)
        #pragma unroll
        for (int ksp = 0; ksp < 2; ++ksp) {
          accq = __builtin_amdgcn_mfma_f32_16x16x32_bf16(aq[tap*2+ksp].v, bf[tap][ksp].v, accq, 0, 0, 0);
          acck = __builtin_amdgcn_mfma_f32_16x16x32_bf16(ak[tap*2+ksp].v, bf[tap][ksp].v, acck, 0, 0, 0);
        }
      #pragma unroll
      for (int ksp = 0; ksp < 2; ++ksp)
        accv = __builtin_amdgcn_mfma_f32_16x16x32_bf16(av2[ksp].v, bf[1][ksp].v, accv, 0, 0, 0);

      const int t = t0 + c15;
      const int rotq = (dblk + t) & 7;
      const unsigned q01 = pk2((accq[0]+bqv[0])*kScale, (accq[1]+bqv[1])*kScale);
      const unsigned q23 = pk2((accq[2]+bqv[2])*kScale, (accq[3]+bqv[3])*kScale);
      *(int2*)(QT + t*64 + rotq*8 + (quad&1)*4) = make_int2((int)q01, (int)q23);
      const unsigned k01 = pk2(acck[0]+bkv[0], acck[1]+bkv[1]);
      const unsigned k23 = pk2(acck[2]+bkv[2], acck[3]+bkv[3]);
      *(int2*)(KT + t*64 + rotq*8 + (quad&1)*4) = make_int2((int)k01, (int)k23);
      #pragma unroll
      for (int r = 0; r < 4; ++r) {
        const int d = dbase + r;
        VTT[d*64 + ((((t>>3) + d) & 7) << 3) + (t & 7)] = f2bfu(accv[r] + b1v[r]);
      }
    }
  }
  __syncthreads();   // also protects XT reads before osT overlay writes

  // ---- attention via MFMA: wave wv handles heads 2wv, 2wv+1 (no-max softmax) ----
  #pragma unroll
  for (int hh = 0; hh < 2; ++hh) {
    const int h = wv*2 + hh;
    B8 vb[2];
    #pragma unroll
    for (int ksp = 0; ksp < 2; ++ksp) {
      if (c15 < 8) {
        const int dr = h*8 + c15;
        vb[ksp].i = *(const int4*)(VTT + dr*64 + (((ksp*4 + quad + dr) & 7) << 3));
      } else vb[ksp].i = make_int4(0,0,0,0);
    }
    #pragma unroll
    for (int nt = 0; nt < 3; ++nt) {
      B8 qb;
      if (quad == 0) {
        const int t = nt*16 + c15;
        qb.i = *(const int4*)(QT + t*64 + (((h + t) & 7) << 3));
      } else qb.i = make_int4(0,0,0,0);
      f32x4 sa[3];
      #pragma unroll
      for (int ms = 0; ms < 3; ++ms) {
        B8 ka;
        if (quad == 0) {
          const int s = ms*16 + c15;
          ka.i = *(const int4*)(KT + s*64 + (((h + s) & 7) << 3));
        } else ka.i = make_int4(0,0,0,0);
        f32x4 z = {0.f,0.f,0.f,0.f};
        sa[ms] = __builtin_amdgcn_mfma_f32_16x16x32_bf16(ka.v, qb.v, z, 0, 0, 0);
      }
      // no-max softmax: scores bounded, exp(s) safe in fp32
      float p[3][4]; float es = 0.f;
      #pragma unroll
      for (int ms = 0; ms < 3; ++ms)
        #pragma unroll
        for (int r = 0; r < 4; ++r) { p[ms][r] = __expf(sa[ms][r]); es += p[ms][r]; }
      es += __shfl_xor(es, 16, 64);
      es += __shfl_xor(es, 32, 64);
      const float inv = __fdividef(1.f, es);
      unsigned pkk[3][2];
      #pragma unroll
      for (int ms = 0; ms < 3; ++ms) {
        pkk[ms][0] = pk2(p[ms][0]*inv, p[ms][1]*inv);
        pkk[ms][1] = pk2(p[ms][2]*inv, p[ms][3]*inv);
      }
      // redistribute P -> PV A-frags (in-register, same-wave shfl)
      const int srcA = c15 + ((2*(quad & 1)) << 4);
      const int srcB = srcA + 16;
      const unsigned w0A = __shfl((int)pkk[0][0], srcA, 64), w0B = __shfl((int)pkk[1][0], srcA, 64);
      const unsigned w1A = __shfl((int)pkk[0][1], srcA, 64), w1B = __shfl((int)pkk[1][1], srcA, 64);
      const unsigned w2A = __shfl((int)pkk[0][0], srcB, 64), w2B = __shfl((int)pkk[1][0], srcB, 64);
      const unsigned w3A = __shfl((int)pkk[0][1], srcB, 64), w3B = __shfl((int)pkk[1][1], srcB, 64);
      const bool hi = quad >= 2;
      B8 a0;
      a0.i = make_int4((int)(hi ? w0B : w0A), (int)(hi ? w1B : w1A),
                       (int)(hi ? w2B : w2A), (int)(hi ? w3B : w3A));
      const int srcC = (c15 + ((2*quad) << 4)) & 63;
      const int srcD = (srcC + 16) & 63;
      const unsigned y0 = __shfl((int)pkk[2][0], srcC, 64), y1 = __shfl((int)pkk[2][1], srcC, 64);
      const unsigned y2 = __shfl((int)pkk[2][0], srcD, 64), y3 = __shfl((int)pkk[2][1], srcD, 64);
      B8 a1;
      if (quad < 2) a1.i = make_int4((int)y0, (int)y1, (int)y2, (int)y3);
      else          a1.i = make_int4(0,0,0,0);
      // PV
      f32x4 ov = {0.f,0.f,0.f,0.f};
      ov = __builtin_amdgcn_mfma_f32_16x16x32_bf16(a0.v, vb[0].v, ov, 0, 0, 0);
      ov = __builtin_amdgcn_mfma_f32_16x16x32_bf16(a1.v, vb[1].v, ov, 0, 0, 0);
      if (c15 < 8) {
        #pragma unroll
        for (int r = 0; r < 4; ++r) {
          const int t = nt*16 + quad*4 + r;
          osT[t*64 + (((h + t) & 7) << 3) + c15] = f2bfu(ov[r]);
        }
      }
    }
  }
  __syncthreads();

  // ---- W2 projection via MFMA -> qs ----
  {
    const int dqr = wv*16 + c15;
    B8 a2[2];
    #pragma unroll
    for (int ksp = 0; ksp < 2; ++ksp)
      a2[ksp].i = *(const int4*)(ws + kW2Off + dqr*64 + ksp*32 + quad*8);
    float b2v[4];
    #pragma unroll
    for (int r = 0; r < 4; ++r) b2v[r] = b2[wv*16 + quad*4 + r];
    for (int i = 0; i < 3; ++i) {
      const int t0 = i * 16;
      f32x4 acc = {0.f,0.f,0.f,0.f};
      #pragma unroll
      for (int ksp = 0; ksp < 2; ++ksp) {
        const int r = t0 + c15;
        B8 bo; bo.i = *(const int4*)(osT + r*64 + (((ksp*4 + quad) + r) & 7)*8);
        acc = __builtin_amdgcn_mfma_f32_16x16x32_bf16(a2[ksp].v, bo.v, acc, 0, 0, 0);
      }
      #pragma unroll
      for (int r = 0; r < 4; ++r)
        qs[(wv*16 + quad*4 + r)*48 + t0 + c15] = acc[r] + b2v[r];
    }
  }
  __syncthreads();

  // ---- LayerNorm + residual (scratch overlays dead XT/osT region) ----
  float* redm = reinterpret_cast<float*>(lds_h);      // [48][4]
  float* redv = redm + 192;                           // [48][4]
  float* mrs  = redm + 384;                           // [48]
  float* rrs  = redm + 432;                           // [48]
  if (tid < 192) {
    const int t = tid >> 2, grp = tid & 3;
    float sm = 0.f, sq = 0.f;
    #pragma unroll
    for (int i = 0; i < 16; ++i) {
      const float v = qs[(grp*16+i)*48 + t];
      sm += v; sq += v*v;
    }
    redm[t*4+grp] = sm; redv[t*4+grp] = sq;
  }
  __syncthreads();
  if (tid < 48) {
    const int t = tid;
    const float sm = redm[t*4] + redm[t*4+1] + redm[t*4+2] + redm[t*4+3];
    const float sq = redv[t*4] + redv[t*4+1] + redv[t*4+2] + redv[t*4+3];
    const float mean = sm * (1.f/64.f);
    const float var = sq * (1.f/64.f) - mean*mean;
    mrs[t] = mean; rrs[t] = rsqrtf(fmaxf(var, 0.f) + kEps);
  }
  __syncthreads();
  if (tid < 192) {
    const int t = tid >> 2, grp = tid & 3;
    const float mean = mrs[t], rs = rrs[t];
    const size_t base = (((size_t)b*kN + n)*kT + t)*kD + grp*16;
    const float* xp = x + (size_t)b*(kD*kN*kT) + (size_t)n*kT + t;
    #pragma unroll
    for (int i4 = 0; i4 < 4; ++i4) {
      float4 o;
      float* op = (float*)&o;
      #pragma unroll
      for (int e = 0; e < 4; ++e) {
        const int d = grp*16 + i4*4 + e;
        const float tout = qs[d*48 + t];
        const float xv = xp[(size_t)d * (kN*kT)];
        op[e] = xv + (tout - mean)*rs*g0[d] + beta0[d];
      }
      *(float4*)(hout + base + i4*4) = o;
    }
  }
}

// ---------------- Kernel 2: spatial GCN — R3 structure + no-max softmax + adj prefetch ----------------
// 4 waves / 256 thr, LDS 36,864 -> 4 blocks/CU. Optional 2-way rb-split per (b,t).
// adj loads hoisted to iteration start (before score MFMAs) — compiler can't move
// global loads across __syncthreads, so without this their ~200cy L2 latency sits
// naked in the Wb-fill critical path every rb.
__global__ __launch_bounds__(256, 4) void k2_spatial_mfma(
    const float* __restrict__ hsrc, float* __restrict__ hdst,
    const float* __restrict__ adj, const u16t* __restrict__ ws,
    const float* __restrict__ g1, const float* __restrict__ beta1, int nparts)
{
  __shared__ __align__(16) u16t Hs[208*64];
  __shared__ __align__(16) u16t Wb[16*224];
  __shared__ __align__(16) u16t A2[16*64];
  __shared__ float rsum[4][16], lnS[4][16], lnQ[4][16];

  const int tid = threadIdx.x;
  int bt, part;
  if (nparts == 2) { bt = blockIdx.x >> 1; part = blockIdx.x & 1; }
  else             { bt = blockIdx.x;      part = 0; }
  const int b = bt / kT, t = bt % kT;
  const int rbBeg = (part == 0) ? 0 : 7;
  const int rbEnd = (nparts == 2 && part == 0) ? 7 : 13;
  const int wv = tid >> 6, lane = tid & 63;
  const int c15 = lane & 15, quad = lane >> 4;
  const int myf = wv*16 + c15;

  const float g1f = g1[myf], be1f = beta1[myf];

  B8 bth[2];
  #pragma unroll
  for (int ksp = 0; ksp < 2; ++ksp)
    bth[ksp].i = *(const int4*)(ws + kThOff + myf*64 + ksp*32 + quad*8);

  // ---- stage H -> Hs (bf16, rot-swizzled); zero rows 200..207; zero Wb ----
  for (int idx = tid; idx < kN*8; idx += 256) {
    const int n = idx >> 3, j = idx & 7;
    const float* src = hsrc + (((size_t)b*kN + n)*kT + t)*kD + j*8;
    const float4 p0 = *(const float4*)src, p1 = *(const float4*)(src + 4);
    B8 p;
    p.u[0]=f2bfu(p0.x); p.u[1]=f2bfu(p0.y); p.u[2]=f2bfu(p0.z); p.u[3]=f2bfu(p0.w);
    p.u[4]=f2bfu(p1.x); p.u[5]=f2bfu(p1.y); p.u[6]=f2bfu(p1.z); p.u[7]=f2bfu(p1.w);
    *(int4*)(Hs + n*64 + (((j + n) & 7) << 3)) = p.i;
  }
  if (tid < 64) {
    *(int4*)(Hs + (200 + (tid >> 3))*64 + ((tid & 7) << 3)) = make_int4(0,0,0,0);
  }
  for (int idx = tid; idx < (16*224)/8; idx += 256)
    *(int4*)(Wb + idx*8) = make_int4(0,0,0,0);
  __syncthreads();

  // ---- hoisted agg A-fragments: A[row=dA][k=m] = H[m][dA], rb-invariant ----
  const int dA = wv*16 + c15;
  B8 ahi[7];
  #pragma unroll
  for (int ksp = 0; ksp < 6; ++ksp) {
    const int m0 = ksp*32 + quad*8;
    #pragma unroll
    for (int j = 0; j < 8; ++j) {
      const int m = m0 + j;
      ahi[ksp].u[j] = Hs[m*64 + ((((dA>>3) + m) & 7) << 3) + (dA & 7)];
    }
  }
  if (quad == 0) {
    #pragma unroll
    for (int j = 0; j < 8; ++j) {
      const int m = 192 + j;
      ahi[6].u[j] = Hs[m*64 + ((((dA>>3) + m) & 7) << 3) + (dA & 7)];
    }
  } else {
    ahi[6].i = make_int4(0, 0, 0, 0);
  }

  for (int rb = rbBeg; rb < rbEnd; ++rb) {
    const int n0 = rb * 16;
    const bool has4 = (wv == 0);

    // ---- adj prefetch: issue L2 loads now; they complete under the score MFMAs ----
    float adjv[3][4], adj3[4];
    #pragma unroll
    for (int r = 0; r < 4; ++r) {
      const int n = n0 + quad*4 + r;
      const bool vrow = (n < kN);
      const int na = vrow ? n : (kN - 1);
      #pragma unroll
      for (int i = 0; i < 3; ++i) {
        const int m = (wv + 4*i)*16 + c15;
        adjv[i][r] = vrow ? adj[(size_t)na*kN + m] : 0.f;
      }
      adj3[r] = (has4 && c15 < 8 && vrow) ? adj[(size_t)na*kN + 192 + c15] : 0.f;
    }

    B8 afr[2];
    #pragma unroll
    for (int ksp = 0; ksp < 2; ++ksp) {
      const int row = n0 + c15;
      afr[ksp].i = *(const int4*)(Hs + row*64 + (((ksp*4 + quad + row) & 7) << 3));
    }
    f32x4 cs[3];
    #pragma unroll
    for (int i = 0; i < 3; ++i) {
      const int mt = wv + 4*i;
      f32x4 acc = {0.f, 0.f, 0.f, 0.f};
      #pragma unroll
      for (int ksp = 0; ksp < 2; ++ksp) {
        const int row = mt*16 + c15;
        B8 bfr; bfr.i = *(const int4*)(Hs + row*64 + (((ksp*4 + quad + row) & 7) << 3));
        acc = __builtin_amdgcn_mfma_f32_16x16x32_bf16(afr[ksp].v, bfr.v, acc, 0, 0, 0);
      }
      cs[i] = acc;
    }
    f32x4 cs3 = {0.f, 0.f, 0.f, 0.f};
    if (has4) {
      #pragma unroll
      for (int ksp = 0; ksp < 2; ++ksp) {
        const int row = 192 + c15;
        B8 bfr; bfr.i = *(const int4*)(Hs + row*64 + (((ksp*4 + quad + row) & 7) << 3));
        cs3 = __builtin_amdgcn_mfma_f32_16x16x32_bf16(afr[ksp].v, bfr.v, cs3, 0, 0, 0);
      }
    }

    // ---- no-max softmax: p = exp(s/8 - 20); shift cancels in p/sum. One barrier. ----
    float smr[4];
    #pragma unroll
    for (int r = 0; r < 4; ++r) {
      cs[0][r] = __expf(fmaf(cs[0][r], 0.125f, -20.f));
      cs[1][r] = __expf(fmaf(cs[1][r], 0.125f, -20.f));
      cs[2][r] = __expf(fmaf(cs[2][r], 0.125f, -20.f));
      cs3[r]   = (has4 && c15 < 8) ? __expf(fmaf(cs3[r], 0.125f, -20.f)) : 0.f;
      smr[r] = cs[0][r] + cs[1][r] + cs[2][r] + cs3[r];
    }
    #pragma unroll
    for (int off = 1; off <= 8; off <<= 1)
      #pragma unroll
      for (int r = 0; r < 4; ++r) smr[r] += __shfl_xor(smr[r], off, 64);
    if (c15 == 0) {
      #pragma unroll
      for (int r = 0; r < 4; ++r) rsum[wv][quad*4 + r] = smr[r];
    }
    __syncthreads();
    #pragma unroll
    for (int r = 0; r < 4; ++r) {
      const int rr = quad*4 + r;
      const float tot = rsum[0][rr] + rsum[1][rr] + rsum[2][rr] + rsum[3][rr];
      const float inv = __fdividef(0.125f, fmaxf(tot, 1e-30f));
      #pragma unroll
      for (int i = 0; i < 3; ++i) {
        const int m = (wv + 4*i)*16 + c15;
        const float w = cs[i][r] * inv * adjv[i][r];
        Wb[rr*224 + (((m >> 3) + rr) % 28)*8 + (m & 7)] = f2bfu(w);
      }
      if (has4 && c15 < 8) {
        const int m = 192 + c15;
        const float w = cs3[r] * inv * adj3[r];
        Wb[rr*224 + (((m >> 3) + rr) % 28)*8 + (m & 7)] = f2bfu(w);
      }
    }
    __syncthreads();

    // ---- agg: A from hoisted registers, B from Wb ----
    f32x4 ag = {0.f, 0.f, 0.f, 0.f};
    #pragma unroll
    for (int ksp = 0; ksp < 7; ++ksp) {
      B8 bw; bw.i = *(const int4*)(Wb + c15*224 + ((ksp*4 + quad + c15) % 28)*8);
      ag = __builtin_amdgcn_mfma_f32_16x16x32_bf16(ahi[ksp].v, bw.v, ag, 0, 0, 0);
    }
    {
      const int dbase = wv*16 + quad*4;
      #pragma unroll
      for (int r = 0; r < 4; ++r) {
        const int d = dbase + r;
        A2[c15*64 + (((d >> 3) + c15) & 7)*8 + (d & 7)] = f2bfu(ag[r]);
      }
    }
    __syncthreads();

    f32x4 o = {0.f, 0.f, 0.f, 0.f};
    #pragma unroll
    for (int ksp = 0; ksp < 2; ++ksp) {
      B8 a; a.i = *(const int4*)(A2 + c15*64 + (((ksp*4 + quad + c15) & 7) << 3));
      o = __builtin_amdgcn_mfma_f32_16x16x32_bf16(a.v, bth[ksp].v, o, 0, 0, 0);
    }
    float vr[4], ps[4], pq[4];
    #pragma unroll
    for (int r = 0; r < 4; ++r) {
      vr[r] = fmaxf(o[r], 0.f);
      ps[r] = vr[r]; pq[r] = vr[r]*vr[r];
    }
    #pragma unroll
    for (int off = 1; off <= 8; off <<= 1)
      #pragma unroll
      for (int r = 0; r < 4; ++r) {
        ps[r] += __shfl_xor(ps[r], off, 64);
        pq[r] += __shfl_xor(pq[r], off, 64);
      }
    if (c15 == 0) {
      #pragma unroll
      for (int r = 0; r < 4; ++r) { lnS[wv][quad*4+r] = ps[r]; lnQ[wv][quad*4+r] = pq[r]; }
    }
    __syncthreads();
    #pragma unroll
    for (int r = 0; r < 4; ++r) {
      const int rr = quad*4 + r, n = n0 + rr;
      const float S = lnS[0][rr] + lnS[1][rr] + lnS[2][rr] + lnS[3][rr];
      const float Q = lnQ[0][rr] + lnQ[1][rr] + lnQ[2][rr] + lnQ[3][rr];
      const float mean = S * (1.f/64.f);
      const float var = Q * (1.f/64.f) - mean*mean;
      const float rs = rsqrtf(fmaxf(var, 0.f) + kEps);
      if (n < kN) {
        const float sout = (vr[r] - mean)*rs*g1f + be1f;
        const size_t oi = (((size_t)b*kN + n)*kT + t)*kD + myf;
        hdst[oi] = hsrc[oi] + sout;
      }
    }
  }
}

} // namespace

extern "C" void kernel_launch(void* const* d_in, const int* in_sizes, int n_in,
                              void* d_out, int out_size, void* d_ws, size_t ws_size,
                              hipStream_t stream) {
  const float* x     = (const float*)d_in[0];
  const float* adj   = (const float*)d_in[1];
  const float* Wq    = (const float*)d_in[2];
  const float* bq    = (const float*)d_in[3];
  const float* Wk    = (const float*)d_in[4];
  const float* bk    = (const float*)d_in[5];
  const float* W1    = (const float*)d_in[6];
  const float* b1    = (const float*)d_in[7];
  const float* W2    = (const float*)d_in[8];
  const float* b2    = (const float*)d_in[9];
  const float* Theta = (const float*)d_in[10];
  const float* g0    = (const float*)d_in[11];
  const float* beta0 = (const float*)d_in[12];
  const float* g1    = (const float*)d_in[13];
  const float* beta1 = (const float*)d_in[14];

  u16t* wsb = (u16t*)d_ws;           // bf16 weight cache (73728 B)

  // If the workspace can hold h, stage h there and split k2 2-way per (b,t)
  // (avoids in-place read/write race between the two parts).
  const bool split = ws_size >= kWsWeightBytes + kHBytes;
  float* hbuf = split ? (float*)((char*)d_ws + kWsWeightBytes) : (float*)d_out;
  const int nparts = split ? 2 : 1;

  k0_prep<<<dim3(48), dim3(256), 0, stream>>>(Wq, Wk, W1, W2, Theta, wsb);
  k1_temporal<<<dim3(kB*kN), dim3(256), 0, stream>>>(
      x, wsb, bq, bk, b1, b2, g0, beta0, hbuf);
  k2_spatial_mfma<<<dim3(kB*kT*nparts), dim3(256), 0, stream>>>(
      hbuf, (float*)d_out, adj, wsb, g1, beta1, nparts);
}